// Round 5
// baseline (361.814 us; speedup 1.0000x reference)
//
#include <hip/hip_runtime.h>

// GCN 3-layer: N=50000, E=1.6M, D_IN=256, H=128, D_OUT=64, fp32 in/out.
// R12: bucketed counting sort killed the global-atomic wall (~17G/s ceiling).
// R13/R14: fused SpMM+GEMM; 8 nodes/block restored gather parallelism
//   (occ 73%) but VALUBusy 54% revealed per-gather 64-bit addr arithmetic +
//   barrier-tail as the issue-rate limiters.
// R15: (a) 32-bit-offset addressing for ALL gathers (saddr form: 1 VALU/gather
//   instead of 3-4); (b) bucket scan folded into bin_kernel's last block
//   (done-counter + threadfence; atomic loads bypass stale L1) -- one fewer
//   launch. Structure otherwise identical to R14 (passed).
// Pipeline: initprep -> bin(+scan) -> fusedA2[gemm1|scatter] -> csr ->
//   spmm_gemm<128,GD> -> spmm_gemm<64> -> spmm<64> = 7 launches.
// Requires n <= 65536 (16-bit packing; harness n = 50000).

constexpr int DIN = 256;
constexpr int HID = 128;
constexpr int DOUT = 64;
constexpr int MAXB = 1024;   // max buckets (n <= 65536)
constexpr int BSH = 6;       // 64 nodes per bucket
constexpr int EPB = 8192;    // edges per bin/scatter block

typedef unsigned short ushort_t;
typedef unsigned int uint_t;
typedef __attribute__((ext_vector_type(8))) short bf16x8;
typedef __attribute__((ext_vector_type(4))) float f32x4;

__device__ inline ushort_t f2bf(float f) {
  uint_t u = __float_as_uint(f);
  u += 0x7FFF + ((u >> 16) & 1);  // RNE
  return (ushort_t)(u >> 16);
}
__device__ inline float bf2f(ushort_t b) {
  return __uint_as_float(((uint_t)b) << 16);
}

// 32-bit-offset gather loads: uniform base + (c<<SH | lane_bytes) voffset.
// SH = log2(row bytes). Lets the compiler emit global_load saddr form.
template <int SH>
__device__ inline uint_t ldrow32(const ushort_t* __restrict__ t, int c, uint_t lb) {
  return *(const uint_t*)((const char*)t + ((((uint_t)c) << SH) | lb));
}
template <int SH>
__device__ inline ushort_t ldrow16(const ushort_t* __restrict__ t, int c, uint_t lb) {
  return *(const ushort_t*)((const char*)t + ((((uint_t)c) << SH) | lb));
}
__device__ inline float ldf32(const float* __restrict__ p, int c) {
  return *(const float*)((const char*)p + (((uint_t)c) << 2));
}

// ---------- weight prep (device fn): W[K][F] fp32 -> fragment bf16 hi/lo ----------
// Layout: Bp[t = n/16][s = k/32][lane = (k/8 % 4)*16 + n%16][j = k%8]

__device__ inline void wprep_one(const float* __restrict__ W, ushort_t* __restrict__ Bhi,
                                 ushort_t* __restrict__ Blo, int K, int F, int i) {
  int k = i / F, nn = i % F;
  int t = nn >> 4, s = k >> 5, q = (k >> 3) & 3, j = k & 7;
  int lane = q * 16 + (nn & 15);
  int KS = K >> 5;
  size_t idx = (((size_t)t * KS + s) * 64 + (size_t)lane) * 8 + j;
  float w = W[i];
  ushort_t h = f2bf(w);
  float r = w - bf2f(h);
  Bhi[idx] = h;
  Blo[idx] = f2bf(r);
}

// ---------- init: zero bucket_total + done + wprep x3 ----------

__global__ __launch_bounds__(256) void initprep_kernel(
    int* __restrict__ bucket_total, int* __restrict__ done, int iblocks,
    const float* __restrict__ W1, ushort_t* __restrict__ W1hi, ushort_t* __restrict__ W1lo,
    const float* __restrict__ W2, ushort_t* __restrict__ W2hi, ushort_t* __restrict__ W2lo,
    const float* __restrict__ W3, ushort_t* __restrict__ W3hi, ushort_t* __restrict__ W3lo) {
  if ((int)blockIdx.x < iblocks) {
    int i = blockIdx.x * 256 + threadIdx.x;
    if (i < MAXB) bucket_total[i] = 0;
    if (i == 0) *done = 0;
  } else {
    int idx = ((int)blockIdx.x - iblocks) * 256 + threadIdx.x;
    constexpr int S1 = DIN * HID;        // 32768
    constexpr int S2 = S1 + HID * HID;   // 49152
    constexpr int S3 = S2 + HID * DOUT;  // 57344
    if (idx < S1) wprep_one(W1, W1hi, W1lo, DIN, HID, idx);
    else if (idx < S2) wprep_one(W2, W2hi, W2lo, HID, HID, idx - S1);
    else if (idx < S3) wprep_one(W3, W3hi, W3lo, HID, DOUT, idx - S2);
  }
}

// ---------- bin pass + last-block bucket scan ----------
// Per-block LDS histogram; one returning global atomic per (block,bucket).
// The LAST block (done-counter) performs the exclusive bucket scan inline,
// reading bucket_total via atomicAdd(p,0) (L1-bypassing coherent loads).

__global__ __launch_bounds__(256) void bin_kernel(const int* __restrict__ dst, int e,
    int nbuckets, int* __restrict__ bucket_total, int* __restrict__ block_base,
    int* __restrict__ bucket_base, int* __restrict__ done, int nbin) {
  __shared__ int h[MAXB];
  __shared__ int lastflag;
  int tid = threadIdx.x;
  for (int i = tid; i < nbuckets; i += 256) h[i] = 0;
  __syncthreads();
  int base = blockIdx.x * EPB;
  int end = min(base + EPB, e);
  for (int i = base + tid; i < end; i += 256) atomicAdd(&h[dst[i] >> BSH], 1);
  __syncthreads();
  for (int i = tid; i < nbuckets; i += 256) {
    int v = h[i];
    if (v) block_base[(size_t)blockIdx.x * nbuckets + i] = atomicAdd(&bucket_total[i], v);
  }
  __threadfence();
  __syncthreads();
  if (tid == 0) lastflag = (atomicAdd(done, 1) == nbin - 1) ? 1 : 0;
  __syncthreads();
  if (!lastflag) return;
  // ---- exclusive scan of bucket_total (reuse h[0..255] as sums) ----
  int a[4];
  int ls = 0;
#pragma unroll
  for (int k = 0; k < 4; ++k) {
    int idx = tid * 4 + k;
    a[k] = (idx < nbuckets) ? atomicAdd(&bucket_total[idx], 0) : 0;
    ls += a[k];
  }
  __syncthreads();
  h[tid] = ls;
  __syncthreads();
  for (int off = 1; off < 256; off <<= 1) {
    int u = (tid >= off) ? h[tid - off] : 0;
    __syncthreads();
    h[tid] += u;
    __syncthreads();
  }
  int run = h[tid] - ls;  // exclusive
#pragma unroll
  for (int k = 0; k < 4; ++k) {
    int idx = tid * 4 + k;
    if (idx < nbuckets) bucket_base[idx] = run;
    run += a[k];
  }
  if (tid == 255) bucket_base[nbuckets] = h[255];  // sentinel = e
}

// ---------- split-bf16 MFMA GEMM (device fn) ----------
// 256 threads = 4 waves; 64 rows per block-id; wave w: rows +16w..+16w+15.
// acc = Ahi*Bhi + Alo*Bhi + Ahi*Blo (fp32 accum; lo*lo dropped, ~2^-18 rel).

template <int K, int F, bool SCALE>
__device__ inline void gemm_mfma_dev(const float* __restrict__ X,
    const ushort_t* __restrict__ Bhi, const ushort_t* __restrict__ Blo,
    const float* __restrict__ dinv, ushort_t* __restrict__ T, int n, int bid) {
  constexpr int NT = F / 16;   // n-tiles
  constexpr int KS = K / 32;   // k-steps
  int wave = threadIdx.x >> 6;
  int lane = threadIdx.x & 63;
  int q = lane >> 4;
  int m = lane & 15;
  int arow = bid * 64 + wave * 16 + m;
  bool valid = arow < n;
  const float* xrow = X + (size_t)arow * K;

  f32x4 acc[NT];
#pragma unroll
  for (int t = 0; t < NT; ++t) acc[t] = (f32x4){0.f, 0.f, 0.f, 0.f};

  for (int s = 0; s < KS; ++s) {
    float av[8];
    if (valid) {
      float4 u0 = *(const float4*)(xrow + s * 32 + q * 8);
      float4 u1 = *(const float4*)(xrow + s * 32 + q * 8 + 4);
      av[0] = u0.x; av[1] = u0.y; av[2] = u0.z; av[3] = u0.w;
      av[4] = u1.x; av[5] = u1.y; av[6] = u1.z; av[7] = u1.w;
    } else {
#pragma unroll
      for (int j = 0; j < 8; ++j) av[j] = 0.f;
    }
    bf16x8 ahi, alo;
#pragma unroll
    for (int j = 0; j < 8; ++j) {
      ushort_t h = f2bf(av[j]);
      ahi[j] = (short)h;
      alo[j] = (short)f2bf(av[j] - bf2f(h));
    }
#pragma unroll
    for (int t = 0; t < NT; ++t) {
      size_t boff = (((size_t)t * KS + s) * 64 + (size_t)lane) * 8;
      bf16x8 bh = *(const bf16x8*)(Bhi + boff);
      bf16x8 bl = *(const bf16x8*)(Blo + boff);
      acc[t] = __builtin_amdgcn_mfma_f32_16x16x32_bf16(ahi, bh, acc[t], 0, 0, 0);
      acc[t] = __builtin_amdgcn_mfma_f32_16x16x32_bf16(alo, bh, acc[t], 0, 0, 0);
      acc[t] = __builtin_amdgcn_mfma_f32_16x16x32_bf16(ahi, bl, acc[t], 0, 0, 0);
    }
  }

  int orow_base = bid * 64 + wave * 16 + q * 4;
#pragma unroll
  for (int r = 0; r < 4; ++r) {
    int orow = orow_base + r;
    if (orow >= n) continue;
    float sc = SCALE ? dinv[orow] : 1.0f;
    ushort_t* trow = T + (size_t)orow * F + m;
#pragma unroll
    for (int t = 0; t < NT; ++t) trow[t * 16] = f2bf(sc * acc[t][r]);
  }
}

// ---------- fused A2: [gemm1 unscaled | scatter into buckets] ----------
// scatter: LDS re-histogram gives rank within (block,bucket); position =
// bucket_base[b] + block_base[blk][b] + rank. Zero global atomics.

__global__ __launch_bounds__(256) void fusedA2_kernel(
    const float* __restrict__ X, const ushort_t* __restrict__ Bhi,
    const ushort_t* __restrict__ Blo, ushort_t* __restrict__ T, int n, int gblocks,
    const int* __restrict__ src, const int* __restrict__ dst,
    const int* __restrict__ bucket_base, const int* __restrict__ block_base,
    uint_t* __restrict__ binned, int e, int nbuckets) {
  if ((int)blockIdx.x < gblocks) {
    gemm_mfma_dev<DIN, HID, false>(X, Bhi, Blo, nullptr, T, n, blockIdx.x);
  } else {
    __shared__ int rkh[MAXB];
    __shared__ int cbase[MAXB];
    int tid = threadIdx.x;
    int blk = (int)blockIdx.x - gblocks;
    for (int i = tid; i < nbuckets; i += 256) {
      rkh[i] = 0;
      cbase[i] = bucket_base[i] + block_base[(size_t)blk * nbuckets + i];
    }
    __syncthreads();
    int base = blk * EPB;
    int end = min(base + EPB, e);
    for (int i = base + tid; i < end; i += 256) {
      int d = dst[i];
      int s = src[i];
      int b = d >> BSH;
      int r = atomicAdd(&rkh[b], 1);
      binned[cbase[b] + r] = ((uint_t)d << 16) | (uint_t)s;
    }
  }
}

// ---------- per-bucket CSR build: deg, dinv, row_start, col ----------
// Bucket = contiguous node range -> offsets are bucket-local; no global scan.

__global__ __launch_bounds__(256) void csr_kernel(const uint_t* __restrict__ binned,
    const int* __restrict__ bucket_base, int n, int* __restrict__ row_start,
    int* __restrict__ deg, float* __restrict__ dinv, int* __restrict__ col) {
  __shared__ int cnt[64];
  __shared__ int rk[64];
  __shared__ int rs[64];
  __shared__ int ebs[2];
  int tid = threadIdx.x;
  int b = blockIdx.x;
  int node0 = b << BSH;
  if (tid < 64) { cnt[tid] = 0; rk[tid] = 0; }
  if (tid == 0) { ebs[0] = bucket_base[b]; ebs[1] = bucket_base[b + 1]; }
  __syncthreads();
  int ebase = ebs[0];
  int esz = ebs[1] - ebase;
  for (int i = tid; i < esz; i += 256)
    atomicAdd(&cnt[(int)(binned[ebase + i] >> 16) - node0], 1);
  __syncthreads();
  if (tid < 64) {
    int v = cnt[tid];
    int inc = v;
#pragma unroll
    for (int off = 1; off < 64; off <<= 1) {
      int u = __shfl_up(inc, off, 64);
      if (tid >= off) inc += u;
    }
    rs[tid] = inc - v;  // exclusive within bucket
    int node = node0 + tid;
    if (node < n) {
      deg[node] = v + 1;                      // + self-loop
      dinv[node] = rsqrtf((float)(v + 1));
      row_start[node] = ebase + (inc - v);
    }
  }
  __syncthreads();
  for (int i = tid; i < esz; i += 256) {
    uint_t p = binned[ebase + i];
    int l = (int)(p >> 16) - node0;
    int r = atomicAdd(&rk[l], 1);
    col[ebase + rs[l] + r] = (int)(p & 0xFFFFu);
  }
}

// ---------- fused SpMM + GEMM (inner layers), 8 nodes/block ----------
// Phase 1: 4 waves x 1 dual-node chain each (standalone-spmm structure,
//          6250 blocks, 3x oversubscription). 32-bit saddr gathers.
//          h = relu(dinv*agg + b) -> fp32 LDS agg[16][132]; rows 8-15 zeroed.
// Phase 2: 16(rows, 8 valid)x128 @ 128xFOUT MFMA; 4 waves x NT/4 tiles.
// GD=true (layer 1): input rows unscaled -> gather dinv[c] per edge.

template <int FOUT, bool GD>
__global__ __launch_bounds__(256) void spmm_gemm_kernel(
    const ushort_t* __restrict__ t, const int* __restrict__ row_start,
    const int* __restrict__ deg, const int* __restrict__ col,
    const float* __restrict__ dinv, const float* __restrict__ bias,
    const ushort_t* __restrict__ Bhi, const ushort_t* __restrict__ Blo,
    ushort_t* __restrict__ Tout, int n) {
  constexpr int FIN = 128;      // row = 256 B -> shift 8
  constexpr int NPB = 8;        // nodes per block
  constexpr int LDW = FIN + 4;  // LDS row stride (floats)
  __shared__ float agg[16][LDW];
  int wave = threadIdx.x >> 6;
  int lane = threadIdx.x & 63;
  int tid = threadIdx.x;
  int nb0 = (int)blockIdx.x * NPB;
  uint_t lb = (uint_t)lane << 2;  // lane byte offset within row (uint granules)

  // zero pad rows 8..15 (contiguous) -- disjoint from phase-1 writes
  {
    float* z = &agg[8][0];
    for (int i = tid; i < 8 * LDW; i += 256) z[i] = 0.f;
  }

  // ---- phase 1: gather-aggregate (1 dual-node chain per wave) ----
  {
    int ln0 = wave * 2;
    int n0 = nb0 + ln0;
    int n1 = n0 + 1;
    bool h0 = n0 < n, h1 = n1 < n;
    int rs0 = h0 ? row_start[n0] : 0, e0 = h0 ? deg[n0] - 1 : 0;
    int rs1 = h1 ? row_start[n1] : 0, e1 = h1 ? deg[n1] - 1 : 0;
    float di0 = h0 ? dinv[n0] : 0.f;
    float di1 = h1 ? dinv[n1] : 0.f;
    float bx = bias[2 * lane], by = bias[2 * lane + 1];
    float ax0 = 0.f, ay0 = 0.f, ax1 = 0.f, ay1 = 0.f;
    if (h0) {
      uint_t s0 = ldrow32<8>(t, n0, lb);
      ax0 = bf2f((ushort_t)(s0 & 0xFFFF)); ay0 = bf2f((ushort_t)(s0 >> 16));
      if constexpr (GD) { ax0 *= di0; ay0 *= di0; }
    }
    if (h1) {
      uint_t s1 = ldrow32<8>(t, n1, lb);
      ax1 = bf2f((ushort_t)(s1 & 0xFFFF)); ay1 = bf2f((ushort_t)(s1 >> 16));
      if constexpr (GD) { ax1 *= di1; ay1 *= di1; }
    }
    int p0 = rs0, q0 = rs0 + e0;
    int p1 = rs1, q1 = rs1 + e1;
    while (p0 + 4 <= q0 && p1 + 4 <= q1) {
      int c[8];
      uint_t v[8];
      float dc[8];
#pragma unroll
      for (int j = 0; j < 4; ++j) { c[j] = col[p0 + j]; c[4 + j] = col[p1 + j]; }
#pragma unroll
      for (int j = 0; j < 8; ++j) {
        v[j] = ldrow32<8>(t, c[j], lb);
        if constexpr (GD) dc[j] = ldf32(dinv, c[j]);
      }
#pragma unroll
      for (int j = 0; j < 4; ++j) {
        if constexpr (GD) {
          ax0 = fmaf(dc[j], bf2f((ushort_t)(v[j] & 0xFFFF)), ax0);
          ay0 = fmaf(dc[j], bf2f((ushort_t)(v[j] >> 16)), ay0);
          ax1 = fmaf(dc[4 + j], bf2f((ushort_t)(v[4 + j] & 0xFFFF)), ax1);
          ay1 = fmaf(dc[4 + j], bf2f((ushort_t)(v[4 + j] >> 16)), ay1);
        } else {
          ax0 += bf2f((ushort_t)(v[j] & 0xFFFF));
          ay0 += bf2f((ushort_t)(v[j] >> 16));
          ax1 += bf2f((ushort_t)(v[4 + j] & 0xFFFF));
          ay1 += bf2f((ushort_t)(v[4 + j] >> 16));
        }
      }
      p0 += 4; p1 += 4;
    }
    for (; p0 + 4 <= q0; p0 += 4) {
      int c[4]; uint_t v[4]; float dc[4];
#pragma unroll
      for (int j = 0; j < 4; ++j) c[j] = col[p0 + j];
#pragma unroll
      for (int j = 0; j < 4; ++j) {
        v[j] = ldrow32<8>(t, c[j], lb);
        if constexpr (GD) dc[j] = ldf32(dinv, c[j]);
      }
#pragma unroll
      for (int j = 0; j < 4; ++j) {
        if constexpr (GD) {
          ax0 = fmaf(dc[j], bf2f((ushort_t)(v[j] & 0xFFFF)), ax0);
          ay0 = fmaf(dc[j], bf2f((ushort_t)(v[j] >> 16)), ay0);
        } else {
          ax0 += bf2f((ushort_t)(v[j] & 0xFFFF)); ay0 += bf2f((ushort_t)(v[j] >> 16));
        }
      }
    }
    for (; p0 < q0; ++p0) {
      int c = col[p0];
      uint_t v = ldrow32<8>(t, c, lb);
      if constexpr (GD) {
        float d = ldf32(dinv, c);
        ax0 = fmaf(d, bf2f((ushort_t)(v & 0xFFFF)), ax0);
        ay0 = fmaf(d, bf2f((ushort_t)(v >> 16)), ay0);
      } else {
        ax0 += bf2f((ushort_t)(v & 0xFFFF)); ay0 += bf2f((ushort_t)(v >> 16));
      }
    }
    for (; p1 + 4 <= q1; p1 += 4) {
      int c[4]; uint_t v[4]; float dc[4];
#pragma unroll
      for (int j = 0; j < 4; ++j) c[j] = col[p1 + j];
#pragma unroll
      for (int j = 0; j < 4; ++j) {
        v[j] = ldrow32<8>(t, c[j], lb);
        if constexpr (GD) dc[j] = ldf32(dinv, c[j]);
      }
#pragma unroll
      for (int j = 0; j < 4; ++j) {
        if constexpr (GD) {
          ax1 = fmaf(dc[j], bf2f((ushort_t)(v[j] & 0xFFFF)), ax1);
          ay1 = fmaf(dc[j], bf2f((ushort_t)(v[j] >> 16)), ay1);
        } else {
          ax1 += bf2f((ushort_t)(v[j] & 0xFFFF)); ay1 += bf2f((ushort_t)(v[j] >> 16));
        }
      }
    }
    for (; p1 < q1; ++p1) {
      int c = col[p1];
      uint_t v = ldrow32<8>(t, c, lb);
      if constexpr (GD) {
        float d = ldf32(dinv, c);
        ax1 = fmaf(d, bf2f((ushort_t)(v & 0xFFFF)), ax1);
        ay1 = fmaf(d, bf2f((ushort_t)(v >> 16)), ay1);
      } else {
        ax1 += bf2f((ushort_t)(v & 0xFFFF)); ay1 += bf2f((ushort_t)(v >> 16));
      }
    }
    float2 o0, o1;
    o0.x = h0 ? fmaxf(fmaf(di0, ax0, bx), 0.f) : 0.f;
    o0.y = h0 ? fmaxf(fmaf(di0, ay0, by), 0.f) : 0.f;
    o1.x = h1 ? fmaxf(fmaf(di1, ax1, bx), 0.f) : 0.f;
    o1.y = h1 ? fmaxf(fmaf(di1, ay1, by), 0.f) : 0.f;
    *(float2*)&agg[ln0][2 * lane] = o0;
    *(float2*)&agg[ln0 + 1][2 * lane] = o1;
  }
  __syncthreads();

  // ---- phase 2: (16-row, 8 valid) x 128 @ 128 x FOUT MFMA ----
  constexpr int NT = FOUT / 16;
  constexpr int KS = FIN / 32;
  constexpr int NTW = NT / 4;   // tiles per wave: FOUT=128 -> 2, FOUT=64 -> 1
  int q = lane >> 4, m = lane & 15;
  f32x4 acc[NTW];
#pragma unroll
  for (int tt = 0; tt < NTW; ++tt) acc[tt] = (f32x4){0.f, 0.f, 0.f, 0.f};
  const float* arow = &agg[m][0];
#pragma unroll
  for (int s = 0; s < KS; ++s) {
    float4 u0 = *(const float4*)(arow + s * 32 + q * 8);
    float4 u1 = *(const float4*)(arow + s * 32 + q * 8 + 4);
    float av[8];
    av[0] = u0.x; av[1] = u0.y; av[2] = u0.z; av[3] = u0.w;
    av[4] = u1.x; av[5] = u1.y; av[6] = u1.z; av[7] = u1.w;
    bf16x8 ahi, alo;
#pragma unroll
    for (int j = 0; j < 8; ++j) {
      ushort_t h = f2bf(av[j]);
      ahi[j] = (short)h;
      alo[j] = (short)f2bf(av[j] - bf2f(h));
    }
#pragma unroll
    for (int tt = 0; tt < NTW; ++tt) {
      int tg = wave * NTW + tt;
      size_t boff = (((size_t)tg * KS + s) * 64 + (size_t)lane) * 8;
      bf16x8 bh = *(const bf16x8*)(Bhi + boff);
      bf16x8 bl = *(const bf16x8*)(Blo + boff);
      acc[tt] = __builtin_amdgcn_mfma_f32_16x16x32_bf16(ahi, bh, acc[tt], 0, 0, 0);
      acc[tt] = __builtin_amdgcn_mfma_f32_16x16x32_bf16(alo, bh, acc[tt], 0, 0, 0);
      acc[tt] = __builtin_amdgcn_mfma_f32_16x16x32_bf16(ahi, bl, acc[tt], 0, 0, 0);
    }
  }
#pragma unroll
  for (int r = 0; r < 4; ++r) {
    int row = q * 4 + r;          // tile row; valid if < 8
    if (row >= NPB) continue;
    int orow = nb0 + row;
    if (orow >= n) continue;
    float sc = dinv[orow];
    ushort_t* trow = Tout + (size_t)orow * FOUT + m;
#pragma unroll
    for (int tt = 0; tt < NTW; ++tt)
      trow[(wave * NTW + tt) * 16] = f2bf(sc * acc[tt][r]);
  }
}

// ---------- CSR SpMM (final layer): out = dinv*(T'[d] + sum T'[c]) + b ----------
// T' rows bf16 pre-scaled. TWO destination nodes per wave. 32-bit saddr loads.

template <int F, bool RELU>
__global__ __launch_bounds__(256) void spmm_kernel(const ushort_t* __restrict__ t,
    const int* __restrict__ row_start, const int* __restrict__ deg,
    const int* __restrict__ col, const float* __restrict__ dinv,
    const float* __restrict__ bias, float* __restrict__ out, int n) {
  static_assert(F == 64, "final layer only");
  int gw = (int)((blockIdx.x * 256u + threadIdx.x) >> 6);
  int lane = threadIdx.x & 63;
  int n0 = gw * 2;
  int n1 = n0 + 1;
  if (n0 >= n) return;
  bool h1 = (n1 < n);
  int rs0 = row_start[n0], e0 = deg[n0] - 1;
  int rs1 = h1 ? row_start[n1] : 0, e1 = h1 ? (deg[n1] - 1) : 0;
  float di0 = dinv[n0];
  float di1 = h1 ? dinv[n1] : 0.f;
  uint_t lb = (uint_t)lane << 1;  // row = 128 B -> shift 7

  float a0 = bf2f(ldrow16<7>(t, n0, lb));
  float a1 = h1 ? bf2f(ldrow16<7>(t, n1, lb)) : 0.f;
  int p0 = rs0, q0 = rs0 + e0;
  int p1 = rs1, q1 = rs1 + e1;
  while (p0 + 4 <= q0 && p1 + 4 <= q1) {
    int c[8];
    ushort_t v[8];
#pragma unroll
    for (int j = 0; j < 4; ++j) { c[j] = col[p0 + j]; c[4 + j] = col[p1 + j]; }
#pragma unroll
    for (int j = 0; j < 8; ++j) v[j] = ldrow16<7>(t, c[j], lb);
#pragma unroll
    for (int j = 0; j < 4; ++j) { a0 += bf2f(v[j]); a1 += bf2f(v[4 + j]); }
    p0 += 4; p1 += 4;
  }
  for (; p0 + 4 <= q0; p0 += 4) {
    int c[4]; ushort_t v[4];
#pragma unroll
    for (int j = 0; j < 4; ++j) c[j] = col[p0 + j];
#pragma unroll
    for (int j = 0; j < 4; ++j) v[j] = ldrow16<7>(t, c[j], lb);
#pragma unroll
    for (int j = 0; j < 4; ++j) a0 += bf2f(v[j]);
  }
  for (; p0 < q0; ++p0) a0 += bf2f(ldrow16<7>(t, col[p0], lb));
  for (; p1 + 4 <= q1; p1 += 4) {
    int c[4]; ushort_t v[4];
#pragma unroll
    for (int j = 0; j < 4; ++j) c[j] = col[p1 + j];
#pragma unroll
    for (int j = 0; j < 4; ++j) v[j] = ldrow16<7>(t, c[j], lb);
#pragma unroll
    for (int j = 0; j < 4; ++j) a1 += bf2f(v[j]);
  }
  for (; p1 < q1; ++p1) a1 += bf2f(ldrow16<7>(t, col[p1], lb));
  float b = bias[lane];
  a0 = fmaf(di0, a0, b);
  if constexpr (RELU) a0 = fmaxf(a0, 0.f);
  out[(size_t)n0 * F + lane] = a0;
  if (h1) {
    a1 = fmaf(di1, a1, b);
    if constexpr (RELU) a1 = fmaxf(a1, 0.f);
    out[(size_t)n1 * F + lane] = a1;
  }
}

// ---------- launch ----------

extern "C" void kernel_launch(void* const* d_in, const int* in_sizes, int n_in,
                              void* d_out, int out_size, void* d_ws, size_t ws_size,
                              hipStream_t stream) {
  const float* x  = (const float*)d_in[0];
  const float* W1 = (const float*)d_in[1];
  const float* b1 = (const float*)d_in[2];
  const float* W2 = (const float*)d_in[3];
  const float* b2 = (const float*)d_in[4];
  const float* W3 = (const float*)d_in[5];
  const float* b3 = (const float*)d_in[6];
  const int* ei   = (const int*)d_in[7];  // harness delivers integers as int32

  int n = in_sizes[0] / DIN;
  int e = in_sizes[7] / 2;
  const int* src = ei;
  const int* dst = ei + e;

  char* ws = (char*)d_ws;
  size_t off = 0;
  auto alloc = [&](size_t bytes) -> void* {
    off = (off + 255) & ~(size_t)255;
    void* p = ws + off;
    off += bytes;
    return p;
  };
  int nbuckets = (n + 63) >> BSH;          // <= MAXB for n <= 65536
  int nbin = (e + EPB - 1) / EPB;

  int*      bucket_total = (int*)alloc((size_t)MAXB * 4);
  int*      bucket_base  = (int*)alloc((size_t)(MAXB + 1) * 4);
  int*      done         = (int*)alloc(256);
  int*      block_base   = (int*)alloc((size_t)nbin * nbuckets * 4);
  uint_t*   binned       = (uint_t*)alloc((size_t)e * 4);
  int*      deg          = (int*)alloc((size_t)n * 4);
  float*    dinv         = (float*)alloc((size_t)n * 4);
  int*      row_start    = (int*)alloc((size_t)n * 4);
  int*      col          = (int*)alloc((size_t)e * 4);
  ushort_t* Ta           = (ushort_t*)alloc((size_t)n * HID * 2);  // bf16 rows
  ushort_t* Tb           = (ushort_t*)alloc((size_t)n * HID * 2);  // bf16 rows
  ushort_t* W1hi         = (ushort_t*)alloc((size_t)DIN * HID * 2);
  ushort_t* W1lo         = (ushort_t*)alloc((size_t)DIN * HID * 2);
  ushort_t* W2hi         = (ushort_t*)alloc((size_t)HID * HID * 2);
  ushort_t* W2lo         = (ushort_t*)alloc((size_t)HID * HID * 2);
  ushort_t* W3hi         = (ushort_t*)alloc((size_t)HID * DOUT * 2);
  ushort_t* W3lo         = (ushort_t*)alloc((size_t)HID * DOUT * 2);
  (void)ws_size;

  int gemm_blocks = (n + 63) / 64;
  int sg_blocks = (n + 7) / 8;              // fused spmm_gemm: 8 nodes/block
  int nwaves = (n + 1) / 2;                 // 2 nodes per wave (final spmm)
  int spmm_blocks = (nwaves + 3) / 4;       // 4 waves per block
  constexpr int WPREP_TOTAL = DIN * HID + HID * HID + HID * DOUT;  // 57344
  int wblocks = (WPREP_TOTAL + 255) / 256;  // 224
  int iblocks = MAXB / 256;                 // 4

  initprep_kernel<<<iblocks + wblocks, 256, 0, stream>>>(
      bucket_total, done, iblocks,
      W1, W1hi, W1lo, W2, W2hi, W2lo, W3, W3hi, W3lo);
  bin_kernel<<<nbin, 256, 0, stream>>>(dst, e, nbuckets, bucket_total, block_base,
                                       bucket_base, done, nbin);
  fusedA2_kernel<<<gemm_blocks + nbin, 256, 0, stream>>>(
      x, W1hi, W1lo, Ta, n, gemm_blocks,
      src, dst, bucket_base, block_base, binned, e, nbuckets);
  csr_kernel<<<nbuckets, 256, 0, stream>>>(binned, bucket_base, n, row_start, deg, dinv, col);

  // layer 1 agg + layer 2 GEMM (fused): Ta (unscaled, GD) -> Tb (scaled bf16)
  spmm_gemm_kernel<HID, true><<<sg_blocks, 256, 0, stream>>>(
      Ta, row_start, deg, col, dinv, b1, W2hi, W2lo, Tb, n);
  // layer 2 agg + layer 3 GEMM (fused): Tb -> Ta (n x 64, scaled bf16)
  spmm_gemm_kernel<DOUT, false><<<sg_blocks, 256, 0, stream>>>(
      Tb, row_start, deg, col, dinv, b2, W3hi, W3lo, Ta, n);
  // layer 3 agg (final): Ta -> out (fp32) + b3
  spmm_kernel<DOUT, false><<<spmm_blocks, 256, 0, stream>>>(
      Ta, row_start, deg, col, dinv, b3, (float*)d_out, n);
}

// Round 6
// 356.761 us; speedup vs baseline: 1.0142x; 1.0142x over previous
//
#include <hip/hip_runtime.h>

// GCN 3-layer: N=50000, E=1.6M, D_IN=256, H=128, D_OUT=64, fp32 in/out.
// R12: bucketed counting sort killed the global-atomic wall (~17G/s ceiling).
// R13/R14: fused SpMM+GEMM; 8 nodes/block restores gather parallelism.
// R15: 32-bit saddr gathers helped sg (VALU 54->47, -2us); bin+scan fold
//   REGRESSED (-14us total: threadfence+spin in bin's critical path). 
// R16: (a) revert the fold -> separate scan kernel (R4 structure);
//   (b) half-wave final spmm: lanes 0-31 node A, 32-63 node B, 4B/lane
//   uint gathers (full 128B row per half-wave) -> half the load insts
//   and VALU per edge at same bytes/grid/occupancy.
// Pipeline: initprep -> bin -> scan -> fusedA2[gemm1|scatter] -> csr ->
//   spmm_gemm<128,GD> -> spmm_gemm<64> -> spmm64 = 8 launches.
// Requires n <= 65536 (16-bit packing; harness n = 50000).

constexpr int DIN = 256;
constexpr int HID = 128;
constexpr int DOUT = 64;
constexpr int MAXB = 1024;   // max buckets (n <= 65536)
constexpr int BSH = 6;       // 64 nodes per bucket
constexpr int EPB = 8192;    // edges per bin/scatter block

typedef unsigned short ushort_t;
typedef unsigned int uint_t;
typedef __attribute__((ext_vector_type(8))) short bf16x8;
typedef __attribute__((ext_vector_type(4))) float f32x4;

__device__ inline ushort_t f2bf(float f) {
  uint_t u = __float_as_uint(f);
  u += 0x7FFF + ((u >> 16) & 1);  // RNE
  return (ushort_t)(u >> 16);
}
__device__ inline float bf2f(ushort_t b) {
  return __uint_as_float(((uint_t)b) << 16);
}

// 32-bit-offset gather loads: uniform base + (c<<SH | lane_bytes) voffset.
// SH = log2(row bytes). Lets the compiler emit global_load saddr form.
template <int SH>
__device__ inline uint_t ldrow32(const ushort_t* __restrict__ t, int c, uint_t lb) {
  return *(const uint_t*)((const char*)t + ((((uint_t)c) << SH) | lb));
}
__device__ inline float ldf32(const float* __restrict__ p, int c) {
  return *(const float*)((const char*)p + (((uint_t)c) << 2));
}

// ---------- weight prep (device fn): W[K][F] fp32 -> fragment bf16 hi/lo ----------
// Layout: Bp[t = n/16][s = k/32][lane = (k/8 % 4)*16 + n%16][j = k%8]

__device__ inline void wprep_one(const float* __restrict__ W, ushort_t* __restrict__ Bhi,
                                 ushort_t* __restrict__ Blo, int K, int F, int i) {
  int k = i / F, nn = i % F;
  int t = nn >> 4, s = k >> 5, q = (k >> 3) & 3, j = k & 7;
  int lane = q * 16 + (nn & 15);
  int KS = K >> 5;
  size_t idx = (((size_t)t * KS + s) * 64 + (size_t)lane) * 8 + j;
  float w = W[i];
  ushort_t h = f2bf(w);
  float r = w - bf2f(h);
  Bhi[idx] = h;
  Blo[idx] = f2bf(r);
}

// ---------- init: zero bucket_total + wprep x3 ----------

__global__ __launch_bounds__(256) void initprep_kernel(
    int* __restrict__ bucket_total, int iblocks,
    const float* __restrict__ W1, ushort_t* __restrict__ W1hi, ushort_t* __restrict__ W1lo,
    const float* __restrict__ W2, ushort_t* __restrict__ W2hi, ushort_t* __restrict__ W2lo,
    const float* __restrict__ W3, ushort_t* __restrict__ W3hi, ushort_t* __restrict__ W3lo) {
  if ((int)blockIdx.x < iblocks) {
    int i = blockIdx.x * 256 + threadIdx.x;
    if (i < MAXB) bucket_total[i] = 0;
  } else {
    int idx = ((int)blockIdx.x - iblocks) * 256 + threadIdx.x;
    constexpr int S1 = DIN * HID;        // 32768
    constexpr int S2 = S1 + HID * HID;   // 49152
    constexpr int S3 = S2 + HID * DOUT;  // 57344
    if (idx < S1) wprep_one(W1, W1hi, W1lo, DIN, HID, idx);
    else if (idx < S2) wprep_one(W2, W2hi, W2lo, HID, HID, idx - S1);
    else if (idx < S3) wprep_one(W3, W3hi, W3lo, HID, DOUT, idx - S2);
  }
}

// ---------- bin pass: per-block LDS histogram over buckets ----------
// One returning global atomic per (block,bucket) -> block's base within bucket.

__global__ __launch_bounds__(256) void bin_kernel(const int* __restrict__ dst, int e,
    int nbuckets, int* __restrict__ bucket_total, int* __restrict__ block_base) {
  __shared__ int h[MAXB];
  int tid = threadIdx.x;
  for (int i = tid; i < nbuckets; i += 256) h[i] = 0;
  __syncthreads();
  int base = blockIdx.x * EPB;
  int end = min(base + EPB, e);
  for (int i = base + tid; i < end; i += 256) atomicAdd(&h[dst[i] >> BSH], 1);
  __syncthreads();
  for (int i = tid; i < nbuckets; i += 256) {
    int v = h[i];
    if (v) block_base[(size_t)blockIdx.x * nbuckets + i] = atomicAdd(&bucket_total[i], v);
  }
}

// ---------- bucket scan: exclusive scan of bucket_total (+ sentinel) ----------

__global__ __launch_bounds__(256) void scan_buckets_kernel(const int* __restrict__ total,
    int* __restrict__ base, int nb) {
  __shared__ int sums[256];
  int t = threadIdx.x;
  int a[4];
  int ls = 0;
#pragma unroll
  for (int k = 0; k < 4; ++k) {
    int idx = t * 4 + k;
    a[k] = (idx < nb) ? total[idx] : 0;
    ls += a[k];
  }
  sums[t] = ls;
  __syncthreads();
  for (int off = 1; off < 256; off <<= 1) {
    int u = (t >= off) ? sums[t - off] : 0;
    __syncthreads();
    sums[t] += u;
    __syncthreads();
  }
  int run = sums[t] - ls;  // exclusive
#pragma unroll
  for (int k = 0; k < 4; ++k) {
    int idx = t * 4 + k;
    if (idx < nb) base[idx] = run;
    run += a[k];
  }
  if (t == 255) base[nb] = sums[255];  // sentinel = e
}

// ---------- split-bf16 MFMA GEMM (device fn) ----------
// 256 threads = 4 waves; 64 rows per block-id; wave w: rows +16w..+16w+15.
// acc = Ahi*Bhi + Alo*Bhi + Ahi*Blo (fp32 accum; lo*lo dropped, ~2^-18 rel).

template <int K, int F, bool SCALE>
__device__ inline void gemm_mfma_dev(const float* __restrict__ X,
    const ushort_t* __restrict__ Bhi, const ushort_t* __restrict__ Blo,
    const float* __restrict__ dinv, ushort_t* __restrict__ T, int n, int bid) {
  constexpr int NT = F / 16;   // n-tiles
  constexpr int KS = K / 32;   // k-steps
  int wave = threadIdx.x >> 6;
  int lane = threadIdx.x & 63;
  int q = lane >> 4;
  int m = lane & 15;
  int arow = bid * 64 + wave * 16 + m;
  bool valid = arow < n;
  const float* xrow = X + (size_t)arow * K;

  f32x4 acc[NT];
#pragma unroll
  for (int t = 0; t < NT; ++t) acc[t] = (f32x4){0.f, 0.f, 0.f, 0.f};

  for (int s = 0; s < KS; ++s) {
    float av[8];
    if (valid) {
      float4 u0 = *(const float4*)(xrow + s * 32 + q * 8);
      float4 u1 = *(const float4*)(xrow + s * 32 + q * 8 + 4);
      av[0] = u0.x; av[1] = u0.y; av[2] = u0.z; av[3] = u0.w;
      av[4] = u1.x; av[5] = u1.y; av[6] = u1.z; av[7] = u1.w;
    } else {
#pragma unroll
      for (int j = 0; j < 8; ++j) av[j] = 0.f;
    }
    bf16x8 ahi, alo;
#pragma unroll
    for (int j = 0; j < 8; ++j) {
      ushort_t h = f2bf(av[j]);
      ahi[j] = (short)h;
      alo[j] = (short)f2bf(av[j] - bf2f(h));
    }
#pragma unroll
    for (int t = 0; t < NT; ++t) {
      size_t boff = (((size_t)t * KS + s) * 64 + (size_t)lane) * 8;
      bf16x8 bh = *(const bf16x8*)(Bhi + boff);
      bf16x8 bl = *(const bf16x8*)(Blo + boff);
      acc[t] = __builtin_amdgcn_mfma_f32_16x16x32_bf16(ahi, bh, acc[t], 0, 0, 0);
      acc[t] = __builtin_amdgcn_mfma_f32_16x16x32_bf16(alo, bh, acc[t], 0, 0, 0);
      acc[t] = __builtin_amdgcn_mfma_f32_16x16x32_bf16(ahi, bl, acc[t], 0, 0, 0);
    }
  }

  int orow_base = bid * 64 + wave * 16 + q * 4;
#pragma unroll
  for (int r = 0; r < 4; ++r) {
    int orow = orow_base + r;
    if (orow >= n) continue;
    float sc = SCALE ? dinv[orow] : 1.0f;
    ushort_t* trow = T + (size_t)orow * F + m;
#pragma unroll
    for (int t = 0; t < NT; ++t) trow[t * 16] = f2bf(sc * acc[t][r]);
  }
}

// ---------- fused A2: [gemm1 unscaled | scatter into buckets] ----------
// scatter: LDS re-histogram gives rank within (block,bucket); position =
// bucket_base[b] + block_base[blk][b] + rank. Zero global atomics.

__global__ __launch_bounds__(256) void fusedA2_kernel(
    const float* __restrict__ X, const ushort_t* __restrict__ Bhi,
    const ushort_t* __restrict__ Blo, ushort_t* __restrict__ T, int n, int gblocks,
    const int* __restrict__ src, const int* __restrict__ dst,
    const int* __restrict__ bucket_base, const int* __restrict__ block_base,
    uint_t* __restrict__ binned, int e, int nbuckets) {
  if ((int)blockIdx.x < gblocks) {
    gemm_mfma_dev<DIN, HID, false>(X, Bhi, Blo, nullptr, T, n, blockIdx.x);
  } else {
    __shared__ int rkh[MAXB];
    __shared__ int cbase[MAXB];
    int tid = threadIdx.x;
    int blk = (int)blockIdx.x - gblocks;
    for (int i = tid; i < nbuckets; i += 256) {
      rkh[i] = 0;
      cbase[i] = bucket_base[i] + block_base[(size_t)blk * nbuckets + i];
    }
    __syncthreads();
    int base = blk * EPB;
    int end = min(base + EPB, e);
    for (int i = base + tid; i < end; i += 256) {
      int d = dst[i];
      int s = src[i];
      int b = d >> BSH;
      int r = atomicAdd(&rkh[b], 1);
      binned[cbase[b] + r] = ((uint_t)d << 16) | (uint_t)s;
    }
  }
}

// ---------- per-bucket CSR build: deg, dinv, row_start, col ----------
// Bucket = contiguous node range -> offsets are bucket-local; no global scan.

__global__ __launch_bounds__(256) void csr_kernel(const uint_t* __restrict__ binned,
    const int* __restrict__ bucket_base, int n, int* __restrict__ row_start,
    int* __restrict__ deg, float* __restrict__ dinv, int* __restrict__ col) {
  __shared__ int cnt[64];
  __shared__ int rk[64];
  __shared__ int rs[64];
  __shared__ int ebs[2];
  int tid = threadIdx.x;
  int b = blockIdx.x;
  int node0 = b << BSH;
  if (tid < 64) { cnt[tid] = 0; rk[tid] = 0; }
  if (tid == 0) { ebs[0] = bucket_base[b]; ebs[1] = bucket_base[b + 1]; }
  __syncthreads();
  int ebase = ebs[0];
  int esz = ebs[1] - ebase;
  for (int i = tid; i < esz; i += 256)
    atomicAdd(&cnt[(int)(binned[ebase + i] >> 16) - node0], 1);
  __syncthreads();
  if (tid < 64) {
    int v = cnt[tid];
    int inc = v;
#pragma unroll
    for (int off = 1; off < 64; off <<= 1) {
      int u = __shfl_up(inc, off, 64);
      if (tid >= off) inc += u;
    }
    rs[tid] = inc - v;  // exclusive within bucket
    int node = node0 + tid;
    if (node < n) {
      deg[node] = v + 1;                      // + self-loop
      dinv[node] = rsqrtf((float)(v + 1));
      row_start[node] = ebase + (inc - v);
    }
  }
  __syncthreads();
  for (int i = tid; i < esz; i += 256) {
    uint_t p = binned[ebase + i];
    int l = (int)(p >> 16) - node0;
    int r = atomicAdd(&rk[l], 1);
    col[ebase + rs[l] + r] = (int)(p & 0xFFFFu);
  }
}

// ---------- fused SpMM + GEMM (inner layers), 8 nodes/block ----------
// Phase 1: 4 waves x 1 dual-node chain each (standalone-spmm structure,
//          6250 blocks, 3x oversubscription). 32-bit saddr gathers.
//          h = relu(dinv*agg + b) -> fp32 LDS agg[16][132]; rows 8-15 zeroed.
// Phase 2: 16(rows, 8 valid)x128 @ 128xFOUT MFMA; 4 waves x NT/4 tiles.
// GD=true (layer 1): input rows unscaled -> gather dinv[c] per edge.

template <int FOUT, bool GD>
__global__ __launch_bounds__(256) void spmm_gemm_kernel(
    const ushort_t* __restrict__ t, const int* __restrict__ row_start,
    const int* __restrict__ deg, const int* __restrict__ col,
    const float* __restrict__ dinv, const float* __restrict__ bias,
    const ushort_t* __restrict__ Bhi, const ushort_t* __restrict__ Blo,
    ushort_t* __restrict__ Tout, int n) {
  constexpr int FIN = 128;      // row = 256 B -> shift 8
  constexpr int NPB = 8;        // nodes per block
  constexpr int LDW = FIN + 4;  // LDS row stride (floats)
  __shared__ float agg[16][LDW];
  int wave = threadIdx.x >> 6;
  int lane = threadIdx.x & 63;
  int tid = threadIdx.x;
  int nb0 = (int)blockIdx.x * NPB;
  uint_t lb = (uint_t)lane << 2;  // lane byte offset within row (uint granules)

  // zero pad rows 8..15 (contiguous) -- disjoint from phase-1 writes
  {
    float* z = &agg[8][0];
    for (int i = tid; i < 8 * LDW; i += 256) z[i] = 0.f;
  }

  // ---- phase 1: gather-aggregate (1 dual-node chain per wave) ----
  {
    int ln0 = wave * 2;
    int n0 = nb0 + ln0;
    int n1 = n0 + 1;
    bool h0 = n0 < n, h1 = n1 < n;
    int rs0 = h0 ? row_start[n0] : 0, e0 = h0 ? deg[n0] - 1 : 0;
    int rs1 = h1 ? row_start[n1] : 0, e1 = h1 ? deg[n1] - 1 : 0;
    float di0 = h0 ? dinv[n0] : 0.f;
    float di1 = h1 ? dinv[n1] : 0.f;
    float bx = bias[2 * lane], by = bias[2 * lane + 1];
    float ax0 = 0.f, ay0 = 0.f, ax1 = 0.f, ay1 = 0.f;
    if (h0) {
      uint_t s0 = ldrow32<8>(t, n0, lb);
      ax0 = bf2f((ushort_t)(s0 & 0xFFFF)); ay0 = bf2f((ushort_t)(s0 >> 16));
      if constexpr (GD) { ax0 *= di0; ay0 *= di0; }
    }
    if (h1) {
      uint_t s1 = ldrow32<8>(t, n1, lb);
      ax1 = bf2f((ushort_t)(s1 & 0xFFFF)); ay1 = bf2f((ushort_t)(s1 >> 16));
      if constexpr (GD) { ax1 *= di1; ay1 *= di1; }
    }
    int p0 = rs0, q0 = rs0 + e0;
    int p1 = rs1, q1 = rs1 + e1;
    while (p0 + 4 <= q0 && p1 + 4 <= q1) {
      int c[8];
      uint_t v[8];
      float dc[8];
#pragma unroll
      for (int j = 0; j < 4; ++j) { c[j] = col[p0 + j]; c[4 + j] = col[p1 + j]; }
#pragma unroll
      for (int j = 0; j < 8; ++j) {
        v[j] = ldrow32<8>(t, c[j], lb);
        if constexpr (GD) dc[j] = ldf32(dinv, c[j]);
      }
#pragma unroll
      for (int j = 0; j < 4; ++j) {
        if constexpr (GD) {
          ax0 = fmaf(dc[j], bf2f((ushort_t)(v[j] & 0xFFFF)), ax0);
          ay0 = fmaf(dc[j], bf2f((ushort_t)(v[j] >> 16)), ay0);
          ax1 = fmaf(dc[4 + j], bf2f((ushort_t)(v[4 + j] & 0xFFFF)), ax1);
          ay1 = fmaf(dc[4 + j], bf2f((ushort_t)(v[4 + j] >> 16)), ay1);
        } else {
          ax0 += bf2f((ushort_t)(v[j] & 0xFFFF));
          ay0 += bf2f((ushort_t)(v[j] >> 16));
          ax1 += bf2f((ushort_t)(v[4 + j] & 0xFFFF));
          ay1 += bf2f((ushort_t)(v[4 + j] >> 16));
        }
      }
      p0 += 4; p1 += 4;
    }
    for (; p0 + 4 <= q0; p0 += 4) {
      int c[4]; uint_t v[4]; float dc[4];
#pragma unroll
      for (int j = 0; j < 4; ++j) c[j] = col[p0 + j];
#pragma unroll
      for (int j = 0; j < 4; ++j) {
        v[j] = ldrow32<8>(t, c[j], lb);
        if constexpr (GD) dc[j] = ldf32(dinv, c[j]);
      }
#pragma unroll
      for (int j = 0; j < 4; ++j) {
        if constexpr (GD) {
          ax0 = fmaf(dc[j], bf2f((ushort_t)(v[j] & 0xFFFF)), ax0);
          ay0 = fmaf(dc[j], bf2f((ushort_t)(v[j] >> 16)), ay0);
        } else {
          ax0 += bf2f((ushort_t)(v[j] & 0xFFFF)); ay0 += bf2f((ushort_t)(v[j] >> 16));
        }
      }
    }
    for (; p0 < q0; ++p0) {
      int c = col[p0];
      uint_t v = ldrow32<8>(t, c, lb);
      if constexpr (GD) {
        float d = ldf32(dinv, c);
        ax0 = fmaf(d, bf2f((ushort_t)(v & 0xFFFF)), ax0);
        ay0 = fmaf(d, bf2f((ushort_t)(v >> 16)), ay0);
      } else {
        ax0 += bf2f((ushort_t)(v & 0xFFFF)); ay0 += bf2f((ushort_t)(v >> 16));
      }
    }
    for (; p1 + 4 <= q1; p1 += 4) {
      int c[4]; uint_t v[4]; float dc[4];
#pragma unroll
      for (int j = 0; j < 4; ++j) c[j] = col[p1 + j];
#pragma unroll
      for (int j = 0; j < 4; ++j) {
        v[j] = ldrow32<8>(t, c[j], lb);
        if constexpr (GD) dc[j] = ldf32(dinv, c[j]);
      }
#pragma unroll
      for (int j = 0; j < 4; ++j) {
        if constexpr (GD) {
          ax1 = fmaf(dc[j], bf2f((ushort_t)(v[j] & 0xFFFF)), ax1);
          ay1 = fmaf(dc[j], bf2f((ushort_t)(v[j] >> 16)), ay1);
        } else {
          ax1 += bf2f((ushort_t)(v[j] & 0xFFFF)); ay1 += bf2f((ushort_t)(v[j] >> 16));
        }
      }
    }
    for (; p1 < q1; ++p1) {
      int c = col[p1];
      uint_t v = ldrow32<8>(t, c, lb);
      if constexpr (GD) {
        float d = ldf32(dinv, c);
        ax1 = fmaf(d, bf2f((ushort_t)(v & 0xFFFF)), ax1);
        ay1 = fmaf(d, bf2f((ushort_t)(v >> 16)), ay1);
      } else {
        ax1 += bf2f((ushort_t)(v & 0xFFFF)); ay1 += bf2f((ushort_t)(v >> 16));
      }
    }
    float2 o0, o1;
    o0.x = h0 ? fmaxf(fmaf(di0, ax0, bx), 0.f) : 0.f;
    o0.y = h0 ? fmaxf(fmaf(di0, ay0, by), 0.f) : 0.f;
    o1.x = h1 ? fmaxf(fmaf(di1, ax1, bx), 0.f) : 0.f;
    o1.y = h1 ? fmaxf(fmaf(di1, ay1, by), 0.f) : 0.f;
    *(float2*)&agg[ln0][2 * lane] = o0;
    *(float2*)&agg[ln0 + 1][2 * lane] = o1;
  }
  __syncthreads();

  // ---- phase 2: (16-row, 8 valid) x 128 @ 128 x FOUT MFMA ----
  constexpr int NT = FOUT / 16;
  constexpr int KS = FIN / 32;
  constexpr int NTW = NT / 4;   // tiles per wave: FOUT=128 -> 2, FOUT=64 -> 1
  int q = lane >> 4, m = lane & 15;
  f32x4 acc[NTW];
#pragma unroll
  for (int tt = 0; tt < NTW; ++tt) acc[tt] = (f32x4){0.f, 0.f, 0.f, 0.f};
  const float* arow = &agg[m][0];
#pragma unroll
  for (int s = 0; s < KS; ++s) {
    float4 u0 = *(const float4*)(arow + s * 32 + q * 8);
    float4 u1 = *(const float4*)(arow + s * 32 + q * 8 + 4);
    float av[8];
    av[0] = u0.x; av[1] = u0.y; av[2] = u0.z; av[3] = u0.w;
    av[4] = u1.x; av[5] = u1.y; av[6] = u1.z; av[7] = u1.w;
    bf16x8 ahi, alo;
#pragma unroll
    for (int j = 0; j < 8; ++j) {
      ushort_t h = f2bf(av[j]);
      ahi[j] = (short)h;
      alo[j] = (short)f2bf(av[j] - bf2f(h));
    }
#pragma unroll
    for (int tt = 0; tt < NTW; ++tt) {
      int tg = wave * NTW + tt;
      size_t boff = (((size_t)tg * KS + s) * 64 + (size_t)lane) * 8;
      bf16x8 bh = *(const bf16x8*)(Bhi + boff);
      bf16x8 bl = *(const bf16x8*)(Blo + boff);
      acc[tt] = __builtin_amdgcn_mfma_f32_16x16x32_bf16(ahi, bh, acc[tt], 0, 0, 0);
      acc[tt] = __builtin_amdgcn_mfma_f32_16x16x32_bf16(alo, bh, acc[tt], 0, 0, 0);
      acc[tt] = __builtin_amdgcn_mfma_f32_16x16x32_bf16(ahi, bl, acc[tt], 0, 0, 0);
    }
  }
#pragma unroll
  for (int r = 0; r < 4; ++r) {
    int row = q * 4 + r;          // tile row; valid if < 8
    if (row >= NPB) continue;
    int orow = nb0 + row;
    if (orow >= n) continue;
    float sc = dinv[orow];
    ushort_t* trow = Tout + (size_t)orow * FOUT + m;
#pragma unroll
    for (int tt = 0; tt < NTW; ++tt)
      trow[(wave * NTW + tt) * 16] = f2bf(sc * acc[tt][r]);
  }
}

// ---------- final CSR SpMM, half-wave layout ----------
// F=64 rows (128 B). Lanes 0-31 own node n0, lanes 32-63 own n1: each gather
// is a uint (4 B/lane, full row per half-wave) -> half the load instructions
// and VALU per edge vs the 2B/lane full-wave layout. Same grid/occupancy.
// Tail: clamp col index to col[0] (always valid), predicate the accumulate.

__global__ __launch_bounds__(256) void spmm64_kernel(const ushort_t* __restrict__ t,
    const int* __restrict__ row_start, const int* __restrict__ deg,
    const int* __restrict__ col, const float* __restrict__ dinv,
    const float* __restrict__ bias, float* __restrict__ out, int n) {
  int gw = (int)((blockIdx.x * 256u + threadIdx.x) >> 6);
  int lane = threadIdx.x & 63;
  int half = lane >> 5;
  int hl = lane & 31;
  int n0 = gw * 2;
  if (n0 >= n) return;
  int node = n0 + half;
  bool valid = node < n;
  int vnode = valid ? node : n0;
  int rs = row_start[vnode];
  int e  = valid ? (deg[vnode] - 1) : 0;
  float di = dinv[vnode];
  uint_t lb = (uint_t)hl << 2;

  uint_t su = ldrow32<7>(t, vnode, lb);
  float ax = bf2f((ushort_t)(su & 0xFFFF));
  float ay = bf2f((ushort_t)(su >> 16));

  int emax = max(e, __shfl_xor(e, 32));  // other half's count
  for (int k = 0; k < emax; k += 4) {
    int c[4];
    uint_t v[4];
#pragma unroll
    for (int j = 0; j < 4; ++j) {
      int on = (k + j) < e;
      c[j] = col[on ? (rs + k + j) : 0];
    }
#pragma unroll
    for (int j = 0; j < 4; ++j) v[j] = ldrow32<7>(t, c[j], lb);
#pragma unroll
    for (int j = 0; j < 4; ++j) {
      if ((k + j) < e) {
        ax += bf2f((ushort_t)(v[j] & 0xFFFF));
        ay += bf2f((ushort_t)(v[j] >> 16));
      }
    }
  }
  if (valid) {
    float bx = bias[2 * hl], by = bias[2 * hl + 1];
    ax = fmaf(di, ax, bx);
    ay = fmaf(di, ay, by);
    float2 o;
    o.x = ax;
    o.y = ay;
    *(float2*)(out + (size_t)node * DOUT + 2 * hl) = o;
  }
}

// ---------- launch ----------

extern "C" void kernel_launch(void* const* d_in, const int* in_sizes, int n_in,
                              void* d_out, int out_size, void* d_ws, size_t ws_size,
                              hipStream_t stream) {
  const float* x  = (const float*)d_in[0];
  const float* W1 = (const float*)d_in[1];
  const float* b1 = (const float*)d_in[2];
  const float* W2 = (const float*)d_in[3];
  const float* b2 = (const float*)d_in[4];
  const float* W3 = (const float*)d_in[5];
  const float* b3 = (const float*)d_in[6];
  const int* ei   = (const int*)d_in[7];  // harness delivers integers as int32

  int n = in_sizes[0] / DIN;
  int e = in_sizes[7] / 2;
  const int* src = ei;
  const int* dst = ei + e;

  char* ws = (char*)d_ws;
  size_t off = 0;
  auto alloc = [&](size_t bytes) -> void* {
    off = (off + 255) & ~(size_t)255;
    void* p = ws + off;
    off += bytes;
    return p;
  };
  int nbuckets = (n + 63) >> BSH;          // <= MAXB for n <= 65536
  int nbin = (e + EPB - 1) / EPB;

  int*      bucket_total = (int*)alloc((size_t)MAXB * 4);
  int*      bucket_base  = (int*)alloc((size_t)(MAXB + 1) * 4);
  int*      block_base   = (int*)alloc((size_t)nbin * nbuckets * 4);
  uint_t*   binned       = (uint_t*)alloc((size_t)e * 4);
  int*      deg          = (int*)alloc((size_t)n * 4);
  float*    dinv         = (float*)alloc((size_t)n * 4);
  int*      row_start    = (int*)alloc((size_t)n * 4);
  int*      col          = (int*)alloc((size_t)e * 4);
  ushort_t* Ta           = (ushort_t*)alloc((size_t)n * HID * 2);  // bf16 rows
  ushort_t* Tb           = (ushort_t*)alloc((size_t)n * HID * 2);  // bf16 rows
  ushort_t* W1hi         = (ushort_t*)alloc((size_t)DIN * HID * 2);
  ushort_t* W1lo         = (ushort_t*)alloc((size_t)DIN * HID * 2);
  ushort_t* W2hi         = (ushort_t*)alloc((size_t)HID * HID * 2);
  ushort_t* W2lo         = (ushort_t*)alloc((size_t)HID * HID * 2);
  ushort_t* W3hi         = (ushort_t*)alloc((size_t)HID * DOUT * 2);
  ushort_t* W3lo         = (ushort_t*)alloc((size_t)HID * DOUT * 2);
  (void)ws_size;

  int gemm_blocks = (n + 63) / 64;
  int sg_blocks = (n + 7) / 8;              // fused spmm_gemm: 8 nodes/block
  int nwaves = (n + 1) / 2;                 // 2 nodes per wave (final spmm)
  int spmm_blocks = (nwaves + 3) / 4;       // 4 waves per block
  constexpr int WPREP_TOTAL = DIN * HID + HID * HID + HID * DOUT;  // 57344
  int wblocks = (WPREP_TOTAL + 255) / 256;  // 224
  int iblocks = MAXB / 256;                 // 4

  initprep_kernel<<<iblocks + wblocks, 256, 0, stream>>>(
      bucket_total, iblocks,
      W1, W1hi, W1lo, W2, W2hi, W2lo, W3, W3hi, W3lo);
  bin_kernel<<<nbin, 256, 0, stream>>>(dst, e, nbuckets, bucket_total, block_base);
  scan_buckets_kernel<<<1, 256, 0, stream>>>(bucket_total, bucket_base, nbuckets);
  fusedA2_kernel<<<gemm_blocks + nbin, 256, 0, stream>>>(
      x, W1hi, W1lo, Ta, n, gemm_blocks,
      src, dst, bucket_base, block_base, binned, e, nbuckets);
  csr_kernel<<<nbuckets, 256, 0, stream>>>(binned, bucket_base, n, row_start, deg, dinv, col);

  // layer 1 agg + layer 2 GEMM (fused): Ta (unscaled, GD) -> Tb (scaled bf16)
  spmm_gemm_kernel<HID, true><<<sg_blocks, 256, 0, stream>>>(
      Ta, row_start, deg, col, dinv, b1, W2hi, W2lo, Tb, n);
  // layer 2 agg + layer 3 GEMM (fused): Tb -> Ta (n x 64, scaled bf16)
  spmm_gemm_kernel<DOUT, false><<<sg_blocks, 256, 0, stream>>>(
      Tb, row_start, deg, col, dinv, b2, W3hi, W3lo, Ta, n);
  // layer 3 agg (final): Ta -> out (fp32) + b3
  spmm64_kernel<<<spmm_blocks, 256, 0, stream>>>(
      Ta, row_start, deg, col, dinv, b3, (float*)d_out, n);
}

// Round 7
// 333.762 us; speedup vs baseline: 1.0840x; 1.0689x over previous
//
#include <hip/hip_runtime.h>

// GCN 3-layer: N=50000, E=1.6M, D_IN=256, H=128, D_OUT=64, fp32 in/out.
// R12: bucketed counting sort killed the global-atomic wall (~17G/s ceiling).
// R13-R16: fused SpMM+GEMM at 8 nodes/block; saddr gathers; half-wave spmm64.
// R17: gather is latency x MLP limited (Little's law: 23 waves/CU x 8
//   outstanding / 900ns ~= 52G rows/s = observed). So:
//   (a) dinv pre-scale of Ta fused into csr (64 rows/block, bf16 in-place)
//       -> sg1 GD eliminated: 1.6M fewer gathers in the vmcnt queue;
//   (b) batch-8 joint chains in sg phase 1: 16 row-gathers in flight/wave;
//   (c) spmm64: per-half own-e loop (no emax waste), batch-8.
// Pipeline: initprep -> bin -> scan -> fusedA2[gemm1|scatter] -> csr(+scaleT)
//   -> spmm_gemm<128> -> spmm_gemm<64> -> spmm64 = 8 launches.
// Requires n <= 65536 (16-bit packing; harness n = 50000).

constexpr int DIN = 256;
constexpr int HID = 128;
constexpr int DOUT = 64;
constexpr int MAXB = 1024;   // max buckets (n <= 65536)
constexpr int BSH = 6;       // 64 nodes per bucket
constexpr int EPB = 8192;    // edges per bin/scatter block

typedef unsigned short ushort_t;
typedef unsigned int uint_t;
typedef __attribute__((ext_vector_type(8))) short bf16x8;
typedef __attribute__((ext_vector_type(4))) float f32x4;

__device__ inline ushort_t f2bf(float f) {
  uint_t u = __float_as_uint(f);
  u += 0x7FFF + ((u >> 16) & 1);  // RNE
  return (ushort_t)(u >> 16);
}
__device__ inline float bf2f(ushort_t b) {
  return __uint_as_float(((uint_t)b) << 16);
}

// 32-bit-offset gather loads: uniform base + (c<<SH | lane_bytes) voffset.
// SH = log2(row bytes). Lets the compiler emit global_load saddr form.
template <int SH>
__device__ inline uint_t ldrow32(const ushort_t* __restrict__ t, int c, uint_t lb) {
  return *(const uint_t*)((const char*)t + ((((uint_t)c) << SH) | lb));
}

// ---------- weight prep (device fn): W[K][F] fp32 -> fragment bf16 hi/lo ----------
// Layout: Bp[t = n/16][s = k/32][lane = (k/8 % 4)*16 + n%16][j = k%8]

__device__ inline void wprep_one(const float* __restrict__ W, ushort_t* __restrict__ Bhi,
                                 ushort_t* __restrict__ Blo, int K, int F, int i) {
  int k = i / F, nn = i % F;
  int t = nn >> 4, s = k >> 5, q = (k >> 3) & 3, j = k & 7;
  int lane = q * 16 + (nn & 15);
  int KS = K >> 5;
  size_t idx = (((size_t)t * KS + s) * 64 + (size_t)lane) * 8 + j;
  float w = W[i];
  ushort_t h = f2bf(w);
  float r = w - bf2f(h);
  Bhi[idx] = h;
  Blo[idx] = f2bf(r);
}

// ---------- init: zero bucket_total + wprep x3 ----------

__global__ __launch_bounds__(256) void initprep_kernel(
    int* __restrict__ bucket_total, int iblocks,
    const float* __restrict__ W1, ushort_t* __restrict__ W1hi, ushort_t* __restrict__ W1lo,
    const float* __restrict__ W2, ushort_t* __restrict__ W2hi, ushort_t* __restrict__ W2lo,
    const float* __restrict__ W3, ushort_t* __restrict__ W3hi, ushort_t* __restrict__ W3lo) {
  if ((int)blockIdx.x < iblocks) {
    int i = blockIdx.x * 256 + threadIdx.x;
    if (i < MAXB) bucket_total[i] = 0;
  } else {
    int idx = ((int)blockIdx.x - iblocks) * 256 + threadIdx.x;
    constexpr int S1 = DIN * HID;        // 32768
    constexpr int S2 = S1 + HID * HID;   // 49152
    constexpr int S3 = S2 + HID * DOUT;  // 57344
    if (idx < S1) wprep_one(W1, W1hi, W1lo, DIN, HID, idx);
    else if (idx < S2) wprep_one(W2, W2hi, W2lo, HID, HID, idx - S1);
    else if (idx < S3) wprep_one(W3, W3hi, W3lo, HID, DOUT, idx - S2);
  }
}

// ---------- bin pass: per-block LDS histogram over buckets ----------
// One returning global atomic per (block,bucket) -> block's base within bucket.

__global__ __launch_bounds__(256) void bin_kernel(const int* __restrict__ dst, int e,
    int nbuckets, int* __restrict__ bucket_total, int* __restrict__ block_base) {
  __shared__ int h[MAXB];
  int tid = threadIdx.x;
  for (int i = tid; i < nbuckets; i += 256) h[i] = 0;
  __syncthreads();
  int base = blockIdx.x * EPB;
  int end = min(base + EPB, e);
  for (int i = base + tid; i < end; i += 256) atomicAdd(&h[dst[i] >> BSH], 1);
  __syncthreads();
  for (int i = tid; i < nbuckets; i += 256) {
    int v = h[i];
    if (v) block_base[(size_t)blockIdx.x * nbuckets + i] = atomicAdd(&bucket_total[i], v);
  }
}

// ---------- bucket scan: exclusive scan of bucket_total (+ sentinel) ----------

__global__ __launch_bounds__(256) void scan_buckets_kernel(const int* __restrict__ total,
    int* __restrict__ base, int nb) {
  __shared__ int sums[256];
  int t = threadIdx.x;
  int a[4];
  int ls = 0;
#pragma unroll
  for (int k = 0; k < 4; ++k) {
    int idx = t * 4 + k;
    a[k] = (idx < nb) ? total[idx] : 0;
    ls += a[k];
  }
  sums[t] = ls;
  __syncthreads();
  for (int off = 1; off < 256; off <<= 1) {
    int u = (t >= off) ? sums[t - off] : 0;
    __syncthreads();
    sums[t] += u;
    __syncthreads();
  }
  int run = sums[t] - ls;  // exclusive
#pragma unroll
  for (int k = 0; k < 4; ++k) {
    int idx = t * 4 + k;
    if (idx < nb) base[idx] = run;
    run += a[k];
  }
  if (t == 255) base[nb] = sums[255];  // sentinel = e
}

// ---------- split-bf16 MFMA GEMM (device fn) ----------
// 256 threads = 4 waves; 64 rows per block-id; wave w: rows +16w..+16w+15.
// acc = Ahi*Bhi + Alo*Bhi + Ahi*Blo (fp32 accum; lo*lo dropped, ~2^-18 rel).

template <int K, int F, bool SCALE>
__device__ inline void gemm_mfma_dev(const float* __restrict__ X,
    const ushort_t* __restrict__ Bhi, const ushort_t* __restrict__ Blo,
    const float* __restrict__ dinv, ushort_t* __restrict__ T, int n, int bid) {
  constexpr int NT = F / 16;   // n-tiles
  constexpr int KS = K / 32;   // k-steps
  int wave = threadIdx.x >> 6;
  int lane = threadIdx.x & 63;
  int q = lane >> 4;
  int m = lane & 15;
  int arow = bid * 64 + wave * 16 + m;
  bool valid = arow < n;
  const float* xrow = X + (size_t)arow * K;

  f32x4 acc[NT];
#pragma unroll
  for (int t = 0; t < NT; ++t) acc[t] = (f32x4){0.f, 0.f, 0.f, 0.f};

  for (int s = 0; s < KS; ++s) {
    float av[8];
    if (valid) {
      float4 u0 = *(const float4*)(xrow + s * 32 + q * 8);
      float4 u1 = *(const float4*)(xrow + s * 32 + q * 8 + 4);
      av[0] = u0.x; av[1] = u0.y; av[2] = u0.z; av[3] = u0.w;
      av[4] = u1.x; av[5] = u1.y; av[6] = u1.z; av[7] = u1.w;
    } else {
#pragma unroll
      for (int j = 0; j < 8; ++j) av[j] = 0.f;
    }
    bf16x8 ahi, alo;
#pragma unroll
    for (int j = 0; j < 8; ++j) {
      ushort_t h = f2bf(av[j]);
      ahi[j] = (short)h;
      alo[j] = (short)f2bf(av[j] - bf2f(h));
    }
#pragma unroll
    for (int t = 0; t < NT; ++t) {
      size_t boff = (((size_t)t * KS + s) * 64 + (size_t)lane) * 8;
      bf16x8 bh = *(const bf16x8*)(Bhi + boff);
      bf16x8 bl = *(const bf16x8*)(Blo + boff);
      acc[t] = __builtin_amdgcn_mfma_f32_16x16x32_bf16(ahi, bh, acc[t], 0, 0, 0);
      acc[t] = __builtin_amdgcn_mfma_f32_16x16x32_bf16(alo, bh, acc[t], 0, 0, 0);
      acc[t] = __builtin_amdgcn_mfma_f32_16x16x32_bf16(ahi, bl, acc[t], 0, 0, 0);
    }
  }

  int orow_base = bid * 64 + wave * 16 + q * 4;
#pragma unroll
  for (int r = 0; r < 4; ++r) {
    int orow = orow_base + r;
    if (orow >= n) continue;
    float sc = SCALE ? dinv[orow] : 1.0f;
    ushort_t* trow = T + (size_t)orow * F + m;
#pragma unroll
    for (int t = 0; t < NT; ++t) trow[t * 16] = f2bf(sc * acc[t][r]);
  }
}

// ---------- fused A2: [gemm1 unscaled | scatter into buckets] ----------
// scatter: LDS re-histogram gives rank within (block,bucket); position =
// bucket_base[b] + block_base[blk][b] + rank. Zero global atomics.

__global__ __launch_bounds__(256) void fusedA2_kernel(
    const float* __restrict__ X, const ushort_t* __restrict__ Bhi,
    const ushort_t* __restrict__ Blo, ushort_t* __restrict__ T, int n, int gblocks,
    const int* __restrict__ src, const int* __restrict__ dst,
    const int* __restrict__ bucket_base, const int* __restrict__ block_base,
    uint_t* __restrict__ binned, int e, int nbuckets) {
  if ((int)blockIdx.x < gblocks) {
    gemm_mfma_dev<DIN, HID, false>(X, Bhi, Blo, nullptr, T, n, blockIdx.x);
  } else {
    __shared__ int rkh[MAXB];
    __shared__ int cbase[MAXB];
    int tid = threadIdx.x;
    int blk = (int)blockIdx.x - gblocks;
    for (int i = tid; i < nbuckets; i += 256) {
      rkh[i] = 0;
      cbase[i] = bucket_base[i] + block_base[(size_t)blk * nbuckets + i];
    }
    __syncthreads();
    int base = blk * EPB;
    int end = min(base + EPB, e);
    for (int i = base + tid; i < end; i += 256) {
      int d = dst[i];
      int s = src[i];
      int b = d >> BSH;
      int r = atomicAdd(&rkh[b], 1);
      binned[cbase[b] + r] = ((uint_t)d << 16) | (uint_t)s;
    }
  }
}

// ---------- per-bucket CSR build + Ta pre-scale ----------
// Bucket = contiguous node range -> offsets are bucket-local; no global scan.
// Also scales this bucket's 64 Ta rows by dinv[row] in place (bf16) so the
// downstream sg1 gather needs NO per-edge dinv loads (GD eliminated).

__global__ __launch_bounds__(256) void csr_kernel(const uint_t* __restrict__ binned,
    const int* __restrict__ bucket_base, int n, int* __restrict__ row_start,
    int* __restrict__ deg, float* __restrict__ dinv, int* __restrict__ col,
    ushort_t* __restrict__ Ta) {
  __shared__ int cnt[64];
  __shared__ int rk[64];
  __shared__ int rs[64];
  __shared__ float sdinv[64];
  __shared__ int ebs[2];
  int tid = threadIdx.x;
  int b = blockIdx.x;
  int node0 = b << BSH;
  if (tid < 64) { cnt[tid] = 0; rk[tid] = 0; }
  if (tid == 0) { ebs[0] = bucket_base[b]; ebs[1] = bucket_base[b + 1]; }
  __syncthreads();
  int ebase = ebs[0];
  int esz = ebs[1] - ebase;
  for (int i = tid; i < esz; i += 256)
    atomicAdd(&cnt[(int)(binned[ebase + i] >> 16) - node0], 1);
  __syncthreads();
  if (tid < 64) {
    int v = cnt[tid];
    int inc = v;
#pragma unroll
    for (int off = 1; off < 64; off <<= 1) {
      int u = __shfl_up(inc, off, 64);
      if (tid >= off) inc += u;
    }
    rs[tid] = inc - v;  // exclusive within bucket
    float di = rsqrtf((float)(v + 1));
    sdinv[tid] = di;
    int node = node0 + tid;
    if (node < n) {
      deg[node] = v + 1;                      // + self-loop
      dinv[node] = di;
      row_start[node] = ebase + (inc - v);
    }
  }
  __syncthreads();
  for (int i = tid; i < esz; i += 256) {
    uint_t p = binned[ebase + i];
    int l = (int)(p >> 16) - node0;
    int r = atomicAdd(&rk[l], 1);
    col[ebase + rs[l] + r] = (int)(p & 0xFFFFu);
  }
  // ---- scale Ta rows (bf16 in place): 64 rows x 16 uint4 each ----
  int nrows = min(64, n - node0);
  if (nrows > 0) {
    uint4* tw = (uint4*)Ta + ((size_t)node0 << 4);  // 16 uint4 per row
    int nv4 = nrows << 4;
    for (int i = tid; i < nv4; i += 256) {
      float sc = sdinv[i >> 4];
      uint4 w = tw[i];
      uint_t ww[4] = {w.x, w.y, w.z, w.w};
#pragma unroll
      for (int j = 0; j < 4; ++j) {
        float lo = sc * bf2f((ushort_t)(ww[j] & 0xFFFF));
        float hi = sc * bf2f((ushort_t)(ww[j] >> 16));
        ww[j] = (uint_t)f2bf(lo) | ((uint_t)f2bf(hi) << 16);
      }
      w.x = ww[0]; w.y = ww[1]; w.z = ww[2]; w.w = ww[3];
      tw[i] = w;
    }
  }
}

// ---------- fused SpMM + GEMM (inner layers), 8 nodes/block ----------
// Phase 1: 4 waves x 1 dual-node chain each; rows PRE-SCALED by dinv[row]
//          -> pure adds, no per-edge dinv. Batch-8 joint loop: 16 row-gathers
//          in flight per wave (latency x MLP limited; Little's law R17).
//          h = relu(dinv*agg + b) -> fp32 LDS agg[16][132]; rows 8-15 zeroed.
// Phase 2: 16(rows, 8 valid)x128 @ 128xFOUT MFMA; 4 waves x NT/4 tiles.

template <int FOUT>
__global__ __launch_bounds__(256) void spmm_gemm_kernel(
    const ushort_t* __restrict__ t, const int* __restrict__ row_start,
    const int* __restrict__ deg, const int* __restrict__ col,
    const float* __restrict__ dinv, const float* __restrict__ bias,
    const ushort_t* __restrict__ Bhi, const ushort_t* __restrict__ Blo,
    ushort_t* __restrict__ Tout, int n) {
  constexpr int FIN = 128;      // row = 256 B -> shift 8
  constexpr int NPB = 8;        // nodes per block
  constexpr int LDW = FIN + 4;  // LDS row stride (floats)
  __shared__ float agg[16][LDW];
  int wave = threadIdx.x >> 6;
  int lane = threadIdx.x & 63;
  int tid = threadIdx.x;
  int nb0 = (int)blockIdx.x * NPB;
  uint_t lb = (uint_t)lane << 2;  // lane byte offset within row (uint granules)

  // zero pad rows 8..15 (contiguous) -- disjoint from phase-1 writes
  {
    float* z = &agg[8][0];
    for (int i = tid; i < 8 * LDW; i += 256) z[i] = 0.f;
  }

  // ---- phase 1: gather-aggregate (1 dual-node chain per wave) ----
  {
    int ln0 = wave * 2;
    int n0 = nb0 + ln0;
    int n1 = n0 + 1;
    bool h0 = n0 < n, h1 = n1 < n;
    int rs0 = h0 ? row_start[n0] : 0, e0 = h0 ? deg[n0] - 1 : 0;
    int rs1 = h1 ? row_start[n1] : 0, e1 = h1 ? deg[n1] - 1 : 0;
    float di0 = h0 ? dinv[n0] : 0.f;
    float di1 = h1 ? dinv[n1] : 0.f;
    float bx = bias[2 * lane], by = bias[2 * lane + 1];
    float ax0 = 0.f, ay0 = 0.f, ax1 = 0.f, ay1 = 0.f;
    if (h0) {
      uint_t s0 = ldrow32<8>(t, n0, lb);
      ax0 = bf2f((ushort_t)(s0 & 0xFFFF)); ay0 = bf2f((ushort_t)(s0 >> 16));
    }
    if (h1) {
      uint_t s1 = ldrow32<8>(t, n1, lb);
      ax1 = bf2f((ushort_t)(s1 & 0xFFFF)); ay1 = bf2f((ushort_t)(s1 >> 16));
    }
    int p0 = rs0, q0 = rs0 + e0;
    int p1 = rs1, q1 = rs1 + e1;
    // batch-8 joint: 16 gathers in flight
    while (p0 + 8 <= q0 && p1 + 8 <= q1) {
      int c[16];
      uint_t v[16];
#pragma unroll
      for (int j = 0; j < 8; ++j) { c[j] = col[p0 + j]; c[8 + j] = col[p1 + j]; }
#pragma unroll
      for (int j = 0; j < 16; ++j) v[j] = ldrow32<8>(t, c[j], lb);
#pragma unroll
      for (int j = 0; j < 8; ++j) {
        ax0 += bf2f((ushort_t)(v[j] & 0xFFFF));
        ay0 += bf2f((ushort_t)(v[j] >> 16));
        ax1 += bf2f((ushort_t)(v[8 + j] & 0xFFFF));
        ay1 += bf2f((ushort_t)(v[8 + j] >> 16));
      }
      p0 += 8; p1 += 8;
    }
    // batch-4 joint
    while (p0 + 4 <= q0 && p1 + 4 <= q1) {
      int c[8];
      uint_t v[8];
#pragma unroll
      for (int j = 0; j < 4; ++j) { c[j] = col[p0 + j]; c[4 + j] = col[p1 + j]; }
#pragma unroll
      for (int j = 0; j < 8; ++j) v[j] = ldrow32<8>(t, c[j], lb);
#pragma unroll
      for (int j = 0; j < 4; ++j) {
        ax0 += bf2f((ushort_t)(v[j] & 0xFFFF));
        ay0 += bf2f((ushort_t)(v[j] >> 16));
        ax1 += bf2f((ushort_t)(v[4 + j] & 0xFFFF));
        ay1 += bf2f((ushort_t)(v[4 + j] >> 16));
      }
      p0 += 4; p1 += 4;
    }
    // chain-0 batch-4 tail
    for (; p0 + 4 <= q0; p0 += 4) {
      int c[4]; uint_t v[4];
#pragma unroll
      for (int j = 0; j < 4; ++j) c[j] = col[p0 + j];
#pragma unroll
      for (int j = 0; j < 4; ++j) v[j] = ldrow32<8>(t, c[j], lb);
#pragma unroll
      for (int j = 0; j < 4; ++j) {
        ax0 += bf2f((ushort_t)(v[j] & 0xFFFF)); ay0 += bf2f((ushort_t)(v[j] >> 16));
      }
    }
    for (; p0 < q0; ++p0) {
      uint_t v = ldrow32<8>(t, col[p0], lb);
      ax0 += bf2f((ushort_t)(v & 0xFFFF)); ay0 += bf2f((ushort_t)(v >> 16));
    }
    // chain-1 batch-4 tail
    for (; p1 + 4 <= q1; p1 += 4) {
      int c[4]; uint_t v[4];
#pragma unroll
      for (int j = 0; j < 4; ++j) c[j] = col[p1 + j];
#pragma unroll
      for (int j = 0; j < 4; ++j) v[j] = ldrow32<8>(t, c[j], lb);
#pragma unroll
      for (int j = 0; j < 4; ++j) {
        ax1 += bf2f((ushort_t)(v[j] & 0xFFFF)); ay1 += bf2f((ushort_t)(v[j] >> 16));
      }
    }
    for (; p1 < q1; ++p1) {
      uint_t v = ldrow32<8>(t, col[p1], lb);
      ax1 += bf2f((ushort_t)(v & 0xFFFF)); ay1 += bf2f((ushort_t)(v >> 16));
    }
    float2 o0, o1;
    o0.x = h0 ? fmaxf(fmaf(di0, ax0, bx), 0.f) : 0.f;
    o0.y = h0 ? fmaxf(fmaf(di0, ay0, by), 0.f) : 0.f;
    o1.x = h1 ? fmaxf(fmaf(di1, ax1, bx), 0.f) : 0.f;
    o1.y = h1 ? fmaxf(fmaf(di1, ay1, by), 0.f) : 0.f;
    *(float2*)&agg[ln0][2 * lane] = o0;
    *(float2*)&agg[ln0 + 1][2 * lane] = o1;
  }
  __syncthreads();

  // ---- phase 2: (16-row, 8 valid) x 128 @ 128 x FOUT MFMA ----
  constexpr int NT = FOUT / 16;
  constexpr int KS = FIN / 32;
  constexpr int NTW = NT / 4;   // tiles per wave: FOUT=128 -> 2, FOUT=64 -> 1
  int q = lane >> 4, m = lane & 15;
  f32x4 acc[NTW];
#pragma unroll
  for (int tt = 0; tt < NTW; ++tt) acc[tt] = (f32x4){0.f, 0.f, 0.f, 0.f};
  const float* arow = &agg[m][0];
#pragma unroll
  for (int s = 0; s < KS; ++s) {
    float4 u0 = *(const float4*)(arow + s * 32 + q * 8);
    float4 u1 = *(const float4*)(arow + s * 32 + q * 8 + 4);
    float av[8];
    av[0] = u0.x; av[1] = u0.y; av[2] = u0.z; av[3] = u0.w;
    av[4] = u1.x; av[5] = u1.y; av[6] = u1.z; av[7] = u1.w;
    bf16x8 ahi, alo;
#pragma unroll
    for (int j = 0; j < 8; ++j) {
      ushort_t h = f2bf(av[j]);
      ahi[j] = (short)h;
      alo[j] = (short)f2bf(av[j] - bf2f(h));
    }
#pragma unroll
    for (int tt = 0; tt < NTW; ++tt) {
      int tg = wave * NTW + tt;
      size_t boff = (((size_t)tg * KS + s) * 64 + (size_t)lane) * 8;
      bf16x8 bh = *(const bf16x8*)(Bhi + boff);
      bf16x8 bl = *(const bf16x8*)(Blo + boff);
      acc[tt] = __builtin_amdgcn_mfma_f32_16x16x32_bf16(ahi, bh, acc[tt], 0, 0, 0);
      acc[tt] = __builtin_amdgcn_mfma_f32_16x16x32_bf16(alo, bh, acc[tt], 0, 0, 0);
      acc[tt] = __builtin_amdgcn_mfma_f32_16x16x32_bf16(ahi, bl, acc[tt], 0, 0, 0);
    }
  }
#pragma unroll
  for (int r = 0; r < 4; ++r) {
    int row = q * 4 + r;          // tile row; valid if < 8
    if (row >= NPB) continue;
    int orow = nb0 + row;
    if (orow >= n) continue;
    float sc = dinv[orow];
    ushort_t* trow = Tout + (size_t)orow * FOUT + m;
#pragma unroll
    for (int tt = 0; tt < NTW; ++tt)
      trow[(wave * NTW + tt) * 16] = f2bf(sc * acc[tt][r]);
  }
}

// ---------- final CSR SpMM, half-wave layout ----------
// F=64 rows (128 B). Lanes 0-31 own node n0, lanes 32-63 own n1: each gather
// is a uint (4 B/lane, full row per half-wave). Per-half own-e loop (divergent
// trip counts -- masked lanes stop issuing; no emax waste), batch-8.

__global__ __launch_bounds__(256) void spmm64_kernel(const ushort_t* __restrict__ t,
    const int* __restrict__ row_start, const int* __restrict__ deg,
    const int* __restrict__ col, const float* __restrict__ dinv,
    const float* __restrict__ bias, float* __restrict__ out, int n) {
  int gw = (int)((blockIdx.x * 256u + threadIdx.x) >> 6);
  int lane = threadIdx.x & 63;
  int half = lane >> 5;
  int hl = lane & 31;
  int n0 = gw * 2;
  if (n0 >= n) return;
  int node = n0 + half;
  bool valid = node < n;
  int vnode = valid ? node : n0;
  int rs = row_start[vnode];
  int e  = valid ? (deg[vnode] - 1) : 0;
  float di = dinv[vnode];
  uint_t lb = (uint_t)hl << 2;

  uint_t su = ldrow32<7>(t, vnode, lb);
  float ax = bf2f((ushort_t)(su & 0xFFFF));
  float ay = bf2f((ushort_t)(su >> 16));

  for (int k = 0; k < e; k += 8) {
    int c[8];
    uint_t v[8];
#pragma unroll
    for (int j = 0; j < 8; ++j) c[j] = col[(k + j) < e ? (rs + k + j) : rs];
#pragma unroll
    for (int j = 0; j < 8; ++j) v[j] = ldrow32<7>(t, c[j], lb);
#pragma unroll
    for (int j = 0; j < 8; ++j) {
      if ((k + j) < e) {
        ax += bf2f((ushort_t)(v[j] & 0xFFFF));
        ay += bf2f((ushort_t)(v[j] >> 16));
      }
    }
  }
  if (valid) {
    float bx = bias[2 * hl], by = bias[2 * hl + 1];
    ax = fmaf(di, ax, bx);
    ay = fmaf(di, ay, by);
    float2 o;
    o.x = ax;
    o.y = ay;
    *(float2*)(out + (size_t)node * DOUT + 2 * hl) = o;
  }
}

// ---------- launch ----------

extern "C" void kernel_launch(void* const* d_in, const int* in_sizes, int n_in,
                              void* d_out, int out_size, void* d_ws, size_t ws_size,
                              hipStream_t stream) {
  const float* x  = (const float*)d_in[0];
  const float* W1 = (const float*)d_in[1];
  const float* b1 = (const float*)d_in[2];
  const float* W2 = (const float*)d_in[3];
  const float* b2 = (const float*)d_in[4];
  const float* W3 = (const float*)d_in[5];
  const float* b3 = (const float*)d_in[6];
  const int* ei   = (const int*)d_in[7];  // harness delivers integers as int32

  int n = in_sizes[0] / DIN;
  int e = in_sizes[7] / 2;
  const int* src = ei;
  const int* dst = ei + e;

  char* ws = (char*)d_ws;
  size_t off = 0;
  auto alloc = [&](size_t bytes) -> void* {
    off = (off + 255) & ~(size_t)255;
    void* p = ws + off;
    off += bytes;
    return p;
  };
  int nbuckets = (n + 63) >> BSH;          // <= MAXB for n <= 65536
  int nbin = (e + EPB - 1) / EPB;

  int*      bucket_total = (int*)alloc((size_t)MAXB * 4);
  int*      bucket_base  = (int*)alloc((size_t)(MAXB + 1) * 4);
  int*      block_base   = (int*)alloc((size_t)nbin * nbuckets * 4);
  uint_t*   binned       = (uint_t*)alloc((size_t)e * 4);
  int*      deg          = (int*)alloc((size_t)n * 4);
  float*    dinv         = (float*)alloc((size_t)n * 4);
  int*      row_start    = (int*)alloc((size_t)n * 4);
  int*      col          = (int*)alloc((size_t)e * 4);
  ushort_t* Ta           = (ushort_t*)alloc((size_t)n * HID * 2);  // bf16 rows
  ushort_t* Tb           = (ushort_t*)alloc((size_t)n * HID * 2);  // bf16 rows
  ushort_t* W1hi         = (ushort_t*)alloc((size_t)DIN * HID * 2);
  ushort_t* W1lo         = (ushort_t*)alloc((size_t)DIN * HID * 2);
  ushort_t* W2hi         = (ushort_t*)alloc((size_t)HID * HID * 2);
  ushort_t* W2lo         = (ushort_t*)alloc((size_t)HID * HID * 2);
  ushort_t* W3hi         = (ushort_t*)alloc((size_t)HID * DOUT * 2);
  ushort_t* W3lo         = (ushort_t*)alloc((size_t)HID * DOUT * 2);
  (void)ws_size;

  int gemm_blocks = (n + 63) / 64;
  int sg_blocks = (n + 7) / 8;              // fused spmm_gemm: 8 nodes/block
  int nwaves = (n + 1) / 2;                 // 2 nodes per wave (final spmm)
  int spmm_blocks = (nwaves + 3) / 4;       // 4 waves per block
  constexpr int WPREP_TOTAL = DIN * HID + HID * HID + HID * DOUT;  // 57344
  int wblocks = (WPREP_TOTAL + 255) / 256;  // 224
  int iblocks = MAXB / 256;                 // 4

  initprep_kernel<<<iblocks + wblocks, 256, 0, stream>>>(
      bucket_total, iblocks,
      W1, W1hi, W1lo, W2, W2hi, W2lo, W3, W3hi, W3lo);
  bin_kernel<<<nbin, 256, 0, stream>>>(dst, e, nbuckets, bucket_total, block_base);
  scan_buckets_kernel<<<1, 256, 0, stream>>>(bucket_total, bucket_base, nbuckets);
  fusedA2_kernel<<<gemm_blocks + nbin, 256, 0, stream>>>(
      x, W1hi, W1lo, Ta, n, gemm_blocks,
      src, dst, bucket_base, block_base, binned, e, nbuckets);
  csr_kernel<<<nbuckets, 256, 0, stream>>>(binned, bucket_base, n, row_start,
                                           deg, dinv, col, Ta);

  // layer 1 agg + layer 2 GEMM (fused): Ta (pre-scaled bf16) -> Tb (scaled bf16)
  spmm_gemm_kernel<HID><<<sg_blocks, 256, 0, stream>>>(
      Ta, row_start, deg, col, dinv, b1, W2hi, W2lo, Tb, n);
  // layer 2 agg + layer 3 GEMM (fused): Tb -> Ta (n x 64, scaled bf16)
  spmm_gemm_kernel<DOUT><<<sg_blocks, 256, 0, stream>>>(
      Tb, row_start, deg, col, dinv, b2, W3hi, W3lo, Ta, n);
  // layer 3 agg (final): Ta -> out (fp32) + b3
  spmm64_kernel<<<spmm_blocks, 256, 0, stream>>>(
      Ta, row_start, deg, col, dinv, b3, (float*)d_out, n);
}

// Round 8
// 332.453 us; speedup vs baseline: 1.0883x; 1.0039x over previous
//
#include <hip/hip_runtime.h>

// GCN 3-layer: N=50000, E=1.6M, D_IN=256, H=128, D_OUT=64, fp32 in/out.
// R12: bucketed counting sort killed the global-atomic wall (~17G/s ceiling).
// R13-R17: fused SpMM+GEMM, saddr gathers, batch-8 chains, csr-fused Ta
//   pre-scale (GD gone), half-wave spmm64. sg = 70us each, gather at 2.43TB/s
//   vs 3.22 proven standalone -> residual is fused-block overhead:
//   half-wasted 16-row MFMA tile + barrier tail.
// R18: fill the tile -- 16 nodes/block, 512 threads, 8 waves. Phase 1
//   unchanged per-wave (same 25K total waves); phase 2 full 16-row tile
//   (zero-fill deleted, useful output per MFMA doubles; FOUT=64: waves 4-7
//   retire after barrier). One variable: tile shape.
// Pipeline: initprep -> bin -> scan -> fusedA2[gemm1|scatter] -> csr(+scaleT)
//   -> spmm_gemm<128> -> spmm_gemm<64> -> spmm64 = 8 launches.
// Requires n <= 65536 (16-bit packing; harness n = 50000).

constexpr int DIN = 256;
constexpr int HID = 128;
constexpr int DOUT = 64;
constexpr int MAXB = 1024;   // max buckets (n <= 65536)
constexpr int BSH = 6;       // 64 nodes per bucket
constexpr int EPB = 8192;    // edges per bin/scatter block

typedef unsigned short ushort_t;
typedef unsigned int uint_t;
typedef __attribute__((ext_vector_type(8))) short bf16x8;
typedef __attribute__((ext_vector_type(4))) float f32x4;

__device__ inline ushort_t f2bf(float f) {
  uint_t u = __float_as_uint(f);
  u += 0x7FFF + ((u >> 16) & 1);  // RNE
  return (ushort_t)(u >> 16);
}
__device__ inline float bf2f(ushort_t b) {
  return __uint_as_float(((uint_t)b) << 16);
}

// 32-bit-offset gather loads: uniform base + (c<<SH | lane_bytes) voffset.
// SH = log2(row bytes). Lets the compiler emit global_load saddr form.
template <int SH>
__device__ inline uint_t ldrow32(const ushort_t* __restrict__ t, int c, uint_t lb) {
  return *(const uint_t*)((const char*)t + ((((uint_t)c) << SH) | lb));
}

// ---------- weight prep (device fn): W[K][F] fp32 -> fragment bf16 hi/lo ----------
// Layout: Bp[t = n/16][s = k/32][lane = (k/8 % 4)*16 + n%16][j = k%8]

__device__ inline void wprep_one(const float* __restrict__ W, ushort_t* __restrict__ Bhi,
                                 ushort_t* __restrict__ Blo, int K, int F, int i) {
  int k = i / F, nn = i % F;
  int t = nn >> 4, s = k >> 5, q = (k >> 3) & 3, j = k & 7;
  int lane = q * 16 + (nn & 15);
  int KS = K >> 5;
  size_t idx = (((size_t)t * KS + s) * 64 + (size_t)lane) * 8 + j;
  float w = W[i];
  ushort_t h = f2bf(w);
  float r = w - bf2f(h);
  Bhi[idx] = h;
  Blo[idx] = f2bf(r);
}

// ---------- init: zero bucket_total + wprep x3 ----------

__global__ __launch_bounds__(256) void initprep_kernel(
    int* __restrict__ bucket_total, int iblocks,
    const float* __restrict__ W1, ushort_t* __restrict__ W1hi, ushort_t* __restrict__ W1lo,
    const float* __restrict__ W2, ushort_t* __restrict__ W2hi, ushort_t* __restrict__ W2lo,
    const float* __restrict__ W3, ushort_t* __restrict__ W3hi, ushort_t* __restrict__ W3lo) {
  if ((int)blockIdx.x < iblocks) {
    int i = blockIdx.x * 256 + threadIdx.x;
    if (i < MAXB) bucket_total[i] = 0;
  } else {
    int idx = ((int)blockIdx.x - iblocks) * 256 + threadIdx.x;
    constexpr int S1 = DIN * HID;        // 32768
    constexpr int S2 = S1 + HID * HID;   // 49152
    constexpr int S3 = S2 + HID * DOUT;  // 57344
    if (idx < S1) wprep_one(W1, W1hi, W1lo, DIN, HID, idx);
    else if (idx < S2) wprep_one(W2, W2hi, W2lo, HID, HID, idx - S1);
    else if (idx < S3) wprep_one(W3, W3hi, W3lo, HID, DOUT, idx - S2);
  }
}

// ---------- bin pass: per-block LDS histogram over buckets ----------
// One returning global atomic per (block,bucket) -> block's base within bucket.

__global__ __launch_bounds__(256) void bin_kernel(const int* __restrict__ dst, int e,
    int nbuckets, int* __restrict__ bucket_total, int* __restrict__ block_base) {
  __shared__ int h[MAXB];
  int tid = threadIdx.x;
  for (int i = tid; i < nbuckets; i += 256) h[i] = 0;
  __syncthreads();
  int base = blockIdx.x * EPB;
  int end = min(base + EPB, e);
  for (int i = base + tid; i < end; i += 256) atomicAdd(&h[dst[i] >> BSH], 1);
  __syncthreads();
  for (int i = tid; i < nbuckets; i += 256) {
    int v = h[i];
    if (v) block_base[(size_t)blockIdx.x * nbuckets + i] = atomicAdd(&bucket_total[i], v);
  }
}

// ---------- bucket scan: exclusive scan of bucket_total (+ sentinel) ----------

__global__ __launch_bounds__(256) void scan_buckets_kernel(const int* __restrict__ total,
    int* __restrict__ base, int nb) {
  __shared__ int sums[256];
  int t = threadIdx.x;
  int a[4];
  int ls = 0;
#pragma unroll
  for (int k = 0; k < 4; ++k) {
    int idx = t * 4 + k;
    a[k] = (idx < nb) ? total[idx] : 0;
    ls += a[k];
  }
  sums[t] = ls;
  __syncthreads();
  for (int off = 1; off < 256; off <<= 1) {
    int u = (t >= off) ? sums[t - off] : 0;
    __syncthreads();
    sums[t] += u;
    __syncthreads();
  }
  int run = sums[t] - ls;  // exclusive
#pragma unroll
  for (int k = 0; k < 4; ++k) {
    int idx = t * 4 + k;
    if (idx < nb) base[idx] = run;
    run += a[k];
  }
  if (t == 255) base[nb] = sums[255];  // sentinel = e
}

// ---------- split-bf16 MFMA GEMM (device fn) ----------
// 256 threads = 4 waves; 64 rows per block-id; wave w: rows +16w..+16w+15.
// acc = Ahi*Bhi + Alo*Bhi + Ahi*Blo (fp32 accum; lo*lo dropped, ~2^-18 rel).

template <int K, int F, bool SCALE>
__device__ inline void gemm_mfma_dev(const float* __restrict__ X,
    const ushort_t* __restrict__ Bhi, const ushort_t* __restrict__ Blo,
    const float* __restrict__ dinv, ushort_t* __restrict__ T, int n, int bid) {
  constexpr int NT = F / 16;   // n-tiles
  constexpr int KS = K / 32;   // k-steps
  int wave = threadIdx.x >> 6;
  int lane = threadIdx.x & 63;
  int q = lane >> 4;
  int m = lane & 15;
  int arow = bid * 64 + wave * 16 + m;
  bool valid = arow < n;
  const float* xrow = X + (size_t)arow * K;

  f32x4 acc[NT];
#pragma unroll
  for (int t = 0; t < NT; ++t) acc[t] = (f32x4){0.f, 0.f, 0.f, 0.f};

  for (int s = 0; s < KS; ++s) {
    float av[8];
    if (valid) {
      float4 u0 = *(const float4*)(xrow + s * 32 + q * 8);
      float4 u1 = *(const float4*)(xrow + s * 32 + q * 8 + 4);
      av[0] = u0.x; av[1] = u0.y; av[2] = u0.z; av[3] = u0.w;
      av[4] = u1.x; av[5] = u1.y; av[6] = u1.z; av[7] = u1.w;
    } else {
#pragma unroll
      for (int j = 0; j < 8; ++j) av[j] = 0.f;
    }
    bf16x8 ahi, alo;
#pragma unroll
    for (int j = 0; j < 8; ++j) {
      ushort_t h = f2bf(av[j]);
      ahi[j] = (short)h;
      alo[j] = (short)f2bf(av[j] - bf2f(h));
    }
#pragma unroll
    for (int t = 0; t < NT; ++t) {
      size_t boff = (((size_t)t * KS + s) * 64 + (size_t)lane) * 8;
      bf16x8 bh = *(const bf16x8*)(Bhi + boff);
      bf16x8 bl = *(const bf16x8*)(Blo + boff);
      acc[t] = __builtin_amdgcn_mfma_f32_16x16x32_bf16(ahi, bh, acc[t], 0, 0, 0);
      acc[t] = __builtin_amdgcn_mfma_f32_16x16x32_bf16(alo, bh, acc[t], 0, 0, 0);
      acc[t] = __builtin_amdgcn_mfma_f32_16x16x32_bf16(ahi, bl, acc[t], 0, 0, 0);
    }
  }

  int orow_base = bid * 64 + wave * 16 + q * 4;
#pragma unroll
  for (int r = 0; r < 4; ++r) {
    int orow = orow_base + r;
    if (orow >= n) continue;
    float sc = SCALE ? dinv[orow] : 1.0f;
    ushort_t* trow = T + (size_t)orow * F + m;
#pragma unroll
    for (int t = 0; t < NT; ++t) trow[t * 16] = f2bf(sc * acc[t][r]);
  }
}

// ---------- fused A2: [gemm1 unscaled | scatter into buckets] ----------
// scatter: LDS re-histogram gives rank within (block,bucket); position =
// bucket_base[b] + block_base[blk][b] + rank. Zero global atomics.

__global__ __launch_bounds__(256) void fusedA2_kernel(
    const float* __restrict__ X, const ushort_t* __restrict__ Bhi,
    const ushort_t* __restrict__ Blo, ushort_t* __restrict__ T, int n, int gblocks,
    const int* __restrict__ src, const int* __restrict__ dst,
    const int* __restrict__ bucket_base, const int* __restrict__ block_base,
    uint_t* __restrict__ binned, int e, int nbuckets) {
  if ((int)blockIdx.x < gblocks) {
    gemm_mfma_dev<DIN, HID, false>(X, Bhi, Blo, nullptr, T, n, blockIdx.x);
  } else {
    __shared__ int rkh[MAXB];
    __shared__ int cbase[MAXB];
    int tid = threadIdx.x;
    int blk = (int)blockIdx.x - gblocks;
    for (int i = tid; i < nbuckets; i += 256) {
      rkh[i] = 0;
      cbase[i] = bucket_base[i] + block_base[(size_t)blk * nbuckets + i];
    }
    __syncthreads();
    int base = blk * EPB;
    int end = min(base + EPB, e);
    for (int i = base + tid; i < end; i += 256) {
      int d = dst[i];
      int s = src[i];
      int b = d >> BSH;
      int r = atomicAdd(&rkh[b], 1);
      binned[cbase[b] + r] = ((uint_t)d << 16) | (uint_t)s;
    }
  }
}

// ---------- per-bucket CSR build + Ta pre-scale ----------
// Bucket = contiguous node range -> offsets are bucket-local; no global scan.
// Also scales this bucket's 64 Ta rows by dinv[row] in place (bf16) so the
// downstream sg1 gather needs NO per-edge dinv loads.

__global__ __launch_bounds__(256) void csr_kernel(const uint_t* __restrict__ binned,
    const int* __restrict__ bucket_base, int n, int* __restrict__ row_start,
    int* __restrict__ deg, float* __restrict__ dinv, int* __restrict__ col,
    ushort_t* __restrict__ Ta) {
  __shared__ int cnt[64];
  __shared__ int rk[64];
  __shared__ int rs[64];
  __shared__ float sdinv[64];
  __shared__ int ebs[2];
  int tid = threadIdx.x;
  int b = blockIdx.x;
  int node0 = b << BSH;
  if (tid < 64) { cnt[tid] = 0; rk[tid] = 0; }
  if (tid == 0) { ebs[0] = bucket_base[b]; ebs[1] = bucket_base[b + 1]; }
  __syncthreads();
  int ebase = ebs[0];
  int esz = ebs[1] - ebase;
  for (int i = tid; i < esz; i += 256)
    atomicAdd(&cnt[(int)(binned[ebase + i] >> 16) - node0], 1);
  __syncthreads();
  if (tid < 64) {
    int v = cnt[tid];
    int inc = v;
#pragma unroll
    for (int off = 1; off < 64; off <<= 1) {
      int u = __shfl_up(inc, off, 64);
      if (tid >= off) inc += u;
    }
    rs[tid] = inc - v;  // exclusive within bucket
    float di = rsqrtf((float)(v + 1));
    sdinv[tid] = di;
    int node = node0 + tid;
    if (node < n) {
      deg[node] = v + 1;                      // + self-loop
      dinv[node] = di;
      row_start[node] = ebase + (inc - v);
    }
  }
  __syncthreads();
  for (int i = tid; i < esz; i += 256) {
    uint_t p = binned[ebase + i];
    int l = (int)(p >> 16) - node0;
    int r = atomicAdd(&rk[l], 1);
    col[ebase + rs[l] + r] = (int)(p & 0xFFFFu);
  }
  // ---- scale Ta rows (bf16 in place): 64 rows x 16 uint4 each ----
  int nrows = min(64, n - node0);
  if (nrows > 0) {
    uint4* tw = (uint4*)Ta + ((size_t)node0 << 4);  // 16 uint4 per row
    int nv4 = nrows << 4;
    for (int i = tid; i < nv4; i += 256) {
      float sc = sdinv[i >> 4];
      uint4 w = tw[i];
      uint_t ww[4] = {w.x, w.y, w.z, w.w};
#pragma unroll
      for (int j = 0; j < 4; ++j) {
        float lo = sc * bf2f((ushort_t)(ww[j] & 0xFFFF));
        float hi = sc * bf2f((ushort_t)(ww[j] >> 16));
        ww[j] = (uint_t)f2bf(lo) | ((uint_t)f2bf(hi) << 16);
      }
      w.x = ww[0]; w.y = ww[1]; w.z = ww[2]; w.w = ww[3];
      tw[i] = w;
    }
  }
}

// ---------- fused SpMM + GEMM (inner layers), 16 nodes/block, 8 waves ----------
// Phase 1: 8 waves x 1 dual-node chain (per-wave structure identical to R17;
//          grid 3125 x 8 waves = same 25K waves). Rows pre-scaled by dinv.
// Phase 2: FULL 16-row x 128 @ 128xFOUT MFMA. FOUT=128: 8 waves x 1 tile;
//          FOUT=64: waves 0-3 compute, 4-7 retire after barrier.

template <int FOUT>
__global__ __launch_bounds__(512) void spmm_gemm_kernel(
    const ushort_t* __restrict__ t, const int* __restrict__ row_start,
    const int* __restrict__ deg, const int* __restrict__ col,
    const float* __restrict__ dinv, const float* __restrict__ bias,
    const ushort_t* __restrict__ Bhi, const ushort_t* __restrict__ Blo,
    ushort_t* __restrict__ Tout, int n) {
  constexpr int FIN = 128;      // row = 256 B -> shift 8
  constexpr int NPB = 16;       // nodes per block
  constexpr int LDW = FIN + 4;  // LDS row stride (floats)
  __shared__ float agg[NPB][LDW];
  int wave = threadIdx.x >> 6;  // 0..7
  int lane = threadIdx.x & 63;
  int nb0 = (int)blockIdx.x * NPB;
  uint_t lb = (uint_t)lane << 2;  // lane byte offset within row (uint granules)

  // ---- phase 1: gather-aggregate (1 dual-node chain per wave) ----
  {
    int ln0 = wave * 2;
    int n0 = nb0 + ln0;
    int n1 = n0 + 1;
    bool h0 = n0 < n, h1 = n1 < n;
    int rs0 = h0 ? row_start[n0] : 0, e0 = h0 ? deg[n0] - 1 : 0;
    int rs1 = h1 ? row_start[n1] : 0, e1 = h1 ? deg[n1] - 1 : 0;
    float di0 = h0 ? dinv[n0] : 0.f;
    float di1 = h1 ? dinv[n1] : 0.f;
    float bx = bias[2 * lane], by = bias[2 * lane + 1];
    float ax0 = 0.f, ay0 = 0.f, ax1 = 0.f, ay1 = 0.f;
    if (h0) {
      uint_t s0 = ldrow32<8>(t, n0, lb);
      ax0 = bf2f((ushort_t)(s0 & 0xFFFF)); ay0 = bf2f((ushort_t)(s0 >> 16));
    }
    if (h1) {
      uint_t s1 = ldrow32<8>(t, n1, lb);
      ax1 = bf2f((ushort_t)(s1 & 0xFFFF)); ay1 = bf2f((ushort_t)(s1 >> 16));
    }
    int p0 = rs0, q0 = rs0 + e0;
    int p1 = rs1, q1 = rs1 + e1;
    // batch-8 joint: 16 gathers in flight
    while (p0 + 8 <= q0 && p1 + 8 <= q1) {
      int c[16];
      uint_t v[16];
#pragma unroll
      for (int j = 0; j < 8; ++j) { c[j] = col[p0 + j]; c[8 + j] = col[p1 + j]; }
#pragma unroll
      for (int j = 0; j < 16; ++j) v[j] = ldrow32<8>(t, c[j], lb);
#pragma unroll
      for (int j = 0; j < 8; ++j) {
        ax0 += bf2f((ushort_t)(v[j] & 0xFFFF));
        ay0 += bf2f((ushort_t)(v[j] >> 16));
        ax1 += bf2f((ushort_t)(v[8 + j] & 0xFFFF));
        ay1 += bf2f((ushort_t)(v[8 + j] >> 16));
      }
      p0 += 8; p1 += 8;
    }
    // batch-4 joint
    while (p0 + 4 <= q0 && p1 + 4 <= q1) {
      int c[8];
      uint_t v[8];
#pragma unroll
      for (int j = 0; j < 4; ++j) { c[j] = col[p0 + j]; c[4 + j] = col[p1 + j]; }
#pragma unroll
      for (int j = 0; j < 8; ++j) v[j] = ldrow32<8>(t, c[j], lb);
#pragma unroll
      for (int j = 0; j < 4; ++j) {
        ax0 += bf2f((ushort_t)(v[j] & 0xFFFF));
        ay0 += bf2f((ushort_t)(v[j] >> 16));
        ax1 += bf2f((ushort_t)(v[4 + j] & 0xFFFF));
        ay1 += bf2f((ushort_t)(v[4 + j] >> 16));
      }
      p0 += 4; p1 += 4;
    }
    // chain-0 tail
    for (; p0 + 4 <= q0; p0 += 4) {
      int c[4]; uint_t v[4];
#pragma unroll
      for (int j = 0; j < 4; ++j) c[j] = col[p0 + j];
#pragma unroll
      for (int j = 0; j < 4; ++j) v[j] = ldrow32<8>(t, c[j], lb);
#pragma unroll
      for (int j = 0; j < 4; ++j) {
        ax0 += bf2f((ushort_t)(v[j] & 0xFFFF)); ay0 += bf2f((ushort_t)(v[j] >> 16));
      }
    }
    for (; p0 < q0; ++p0) {
      uint_t v = ldrow32<8>(t, col[p0], lb);
      ax0 += bf2f((ushort_t)(v & 0xFFFF)); ay0 += bf2f((ushort_t)(v >> 16));
    }
    // chain-1 tail
    for (; p1 + 4 <= q1; p1 += 4) {
      int c[4]; uint_t v[4];
#pragma unroll
      for (int j = 0; j < 4; ++j) c[j] = col[p1 + j];
#pragma unroll
      for (int j = 0; j < 4; ++j) v[j] = ldrow32<8>(t, c[j], lb);
#pragma unroll
      for (int j = 0; j < 4; ++j) {
        ax1 += bf2f((ushort_t)(v[j] & 0xFFFF)); ay1 += bf2f((ushort_t)(v[j] >> 16));
      }
    }
    for (; p1 < q1; ++p1) {
      uint_t v = ldrow32<8>(t, col[p1], lb);
      ax1 += bf2f((ushort_t)(v & 0xFFFF)); ay1 += bf2f((ushort_t)(v >> 16));
    }
    float2 o0, o1;
    o0.x = h0 ? fmaxf(fmaf(di0, ax0, bx), 0.f) : 0.f;
    o0.y = h0 ? fmaxf(fmaf(di0, ay0, by), 0.f) : 0.f;
    o1.x = h1 ? fmaxf(fmaf(di1, ax1, bx), 0.f) : 0.f;
    o1.y = h1 ? fmaxf(fmaf(di1, ay1, by), 0.f) : 0.f;
    *(float2*)&agg[ln0][2 * lane] = o0;
    *(float2*)&agg[ln0 + 1][2 * lane] = o1;
  }
  __syncthreads();

  // ---- phase 2: FULL 16-row x 128 @ 128 x FOUT MFMA ----
  constexpr int NT = FOUT / 16;  // 8 (FOUT=128) or 4 (FOUT=64)
  constexpr int KS = FIN / 32;
  if (wave < NT) {
    int q = lane >> 4, m = lane & 15;
    f32x4 acc = (f32x4){0.f, 0.f, 0.f, 0.f};
    const float* arow = &agg[m][0];
#pragma unroll
    for (int s = 0; s < KS; ++s) {
      float4 u0 = *(const float4*)(arow + s * 32 + q * 8);
      float4 u1 = *(const float4*)(arow + s * 32 + q * 8 + 4);
      float av[8];
      av[0] = u0.x; av[1] = u0.y; av[2] = u0.z; av[3] = u0.w;
      av[4] = u1.x; av[5] = u1.y; av[6] = u1.z; av[7] = u1.w;
      bf16x8 ahi, alo;
#pragma unroll
      for (int j = 0; j < 8; ++j) {
        ushort_t h = f2bf(av[j]);
        ahi[j] = (short)h;
        alo[j] = (short)f2bf(av[j] - bf2f(h));
      }
      size_t boff = (((size_t)wave * KS + s) * 64 + (size_t)lane) * 8;
      bf16x8 bh = *(const bf16x8*)(Bhi + boff);
      bf16x8 bl = *(const bf16x8*)(Blo + boff);
      acc = __builtin_amdgcn_mfma_f32_16x16x32_bf16(ahi, bh, acc, 0, 0, 0);
      acc = __builtin_amdgcn_mfma_f32_16x16x32_bf16(alo, bh, acc, 0, 0, 0);
      acc = __builtin_amdgcn_mfma_f32_16x16x32_bf16(ahi, bl, acc, 0, 0, 0);
    }
#pragma unroll
    for (int r = 0; r < 4; ++r) {
      int orow = nb0 + q * 4 + r;
      if (orow >= n) continue;
      float sc = dinv[orow];
      Tout[(size_t)orow * FOUT + wave * 16 + m] = f2bf(sc * acc[r]);
    }
  }
}

// ---------- final CSR SpMM, half-wave layout ----------
// F=64 rows (128 B). Lanes 0-31 own node n0, lanes 32-63 own n1: each gather
// is a uint (4 B/lane, full row per half-wave). Per-half own-e loop, batch-8.

__global__ __launch_bounds__(256) void spmm64_kernel(const ushort_t* __restrict__ t,
    const int* __restrict__ row_start, const int* __restrict__ deg,
    const int* __restrict__ col, const float* __restrict__ dinv,
    const float* __restrict__ bias, float* __restrict__ out, int n) {
  int gw = (int)((blockIdx.x * 256u + threadIdx.x) >> 6);
  int lane = threadIdx.x & 63;
  int half = lane >> 5;
  int hl = lane & 31;
  int n0 = gw * 2;
  if (n0 >= n) return;
  int node = n0 + half;
  bool valid = node < n;
  int vnode = valid ? node : n0;
  int rs = row_start[vnode];
  int e  = valid ? (deg[vnode] - 1) : 0;
  float di = dinv[vnode];
  uint_t lb = (uint_t)hl << 2;

  uint_t su = ldrow32<7>(t, vnode, lb);
  float ax = bf2f((ushort_t)(su & 0xFFFF));
  float ay = bf2f((ushort_t)(su >> 16));

  for (int k = 0; k < e; k += 8) {
    int c[8];
    uint_t v[8];
#pragma unroll
    for (int j = 0; j < 8; ++j) c[j] = col[(k + j) < e ? (rs + k + j) : rs];
#pragma unroll
    for (int j = 0; j < 8; ++j) v[j] = ldrow32<7>(t, c[j], lb);
#pragma unroll
    for (int j = 0; j < 8; ++j) {
      if ((k + j) < e) {
        ax += bf2f((ushort_t)(v[j] & 0xFFFF));
        ay += bf2f((ushort_t)(v[j] >> 16));
      }
    }
  }
  if (valid) {
    float bx = bias[2 * hl], by = bias[2 * hl + 1];
    ax = fmaf(di, ax, bx);
    ay = fmaf(di, ay, by);
    float2 o;
    o.x = ax;
    o.y = ay;
    *(float2*)(out + (size_t)node * DOUT + 2 * hl) = o;
  }
}

// ---------- launch ----------

extern "C" void kernel_launch(void* const* d_in, const int* in_sizes, int n_in,
                              void* d_out, int out_size, void* d_ws, size_t ws_size,
                              hipStream_t stream) {
  const float* x  = (const float*)d_in[0];
  const float* W1 = (const float*)d_in[1];
  const float* b1 = (const float*)d_in[2];
  const float* W2 = (const float*)d_in[3];
  const float* b2 = (const float*)d_in[4];
  const float* W3 = (const float*)d_in[5];
  const float* b3 = (const float*)d_in[6];
  const int* ei   = (const int*)d_in[7];  // harness delivers integers as int32

  int n = in_sizes[0] / DIN;
  int e = in_sizes[7] / 2;
  const int* src = ei;
  const int* dst = ei + e;

  char* ws = (char*)d_ws;
  size_t off = 0;
  auto alloc = [&](size_t bytes) -> void* {
    off = (off + 255) & ~(size_t)255;
    void* p = ws + off;
    off += bytes;
    return p;
  };
  int nbuckets = (n + 63) >> BSH;          // <= MAXB for n <= 65536
  int nbin = (e + EPB - 1) / EPB;

  int*      bucket_total = (int*)alloc((size_t)MAXB * 4);
  int*      bucket_base  = (int*)alloc((size_t)(MAXB + 1) * 4);
  int*      block_base   = (int*)alloc((size_t)nbin * nbuckets * 4);
  uint_t*   binned       = (uint_t*)alloc((size_t)e * 4);
  int*      deg          = (int*)alloc((size_t)n * 4);
  float*    dinv         = (float*)alloc((size_t)n * 4);
  int*      row_start    = (int*)alloc((size_t)n * 4);
  int*      col          = (int*)alloc((size_t)e * 4);
  ushort_t* Ta           = (ushort_t*)alloc((size_t)n * HID * 2);  // bf16 rows
  ushort_t* Tb           = (ushort_t*)alloc((size_t)n * HID * 2);  // bf16 rows
  ushort_t* W1hi         = (ushort_t*)alloc((size_t)DIN * HID * 2);
  ushort_t* W1lo         = (ushort_t*)alloc((size_t)DIN * HID * 2);
  ushort_t* W2hi         = (ushort_t*)alloc((size_t)HID * HID * 2);
  ushort_t* W2lo         = (ushort_t*)alloc((size_t)HID * HID * 2);
  ushort_t* W3hi         = (ushort_t*)alloc((size_t)HID * DOUT * 2);
  ushort_t* W3lo         = (ushort_t*)alloc((size_t)HID * DOUT * 2);
  (void)ws_size;

  int gemm_blocks = (n + 63) / 64;
  int sg_blocks = (n + 15) / 16;            // fused spmm_gemm: 16 nodes/block
  int nwaves = (n + 1) / 2;                 // 2 nodes per wave (final spmm)
  int spmm_blocks = (nwaves + 3) / 4;       // 4 waves per block
  constexpr int WPREP_TOTAL = DIN * HID + HID * HID + HID * DOUT;  // 57344
  int wblocks = (WPREP_TOTAL + 255) / 256;  // 224
  int iblocks = MAXB / 256;                 // 4

  initprep_kernel<<<iblocks + wblocks, 256, 0, stream>>>(
      bucket_total, iblocks,
      W1, W1hi, W1lo, W2, W2hi, W2lo, W3, W3hi, W3lo);
  bin_kernel<<<nbin, 256, 0, stream>>>(dst, e, nbuckets, bucket_total, block_base);
  scan_buckets_kernel<<<1, 256, 0, stream>>>(bucket_total, bucket_base, nbuckets);
  fusedA2_kernel<<<gemm_blocks + nbin, 256, 0, stream>>>(
      x, W1hi, W1lo, Ta, n, gemm_blocks,
      src, dst, bucket_base, block_base, binned, e, nbuckets);
  csr_kernel<<<nbuckets, 256, 0, stream>>>(binned, bucket_base, n, row_start,
                                           deg, dinv, col, Ta);

  // layer 1 agg + layer 2 GEMM (fused): Ta (pre-scaled bf16) -> Tb (scaled bf16)
  spmm_gemm_kernel<HID><<<sg_blocks, 512, 0, stream>>>(
      Ta, row_start, deg, col, dinv, b1, W2hi, W2lo, Tb, n);
  // layer 2 agg + layer 3 GEMM (fused): Tb -> Ta (n x 64, scaled bf16)
  spmm_gemm_kernel<DOUT><<<sg_blocks, 512, 0, stream>>>(
      Tb, row_start, deg, col, dinv, b2, W3hi, W3lo, Ta, n);
  // layer 3 agg (final): Ta -> out (fp32) + b3
  spmm64_kernel<<<spmm_blocks, 256, 0, stream>>>(
      Ta, row_start, deg, col, dinv, b3, (float*)d_out, n);
}

// Round 9
// 330.051 us; speedup vs baseline: 1.0962x; 1.0073x over previous
//
#include <hip/hip_runtime.h>

// GCN 3-layer: N=50000, E=1.6M, D_IN=256, H=128, D_OUT=64, fp32 in/out.
// R12: bucketed counting sort killed the global-atomic wall (~17G/s ceiling).
// R13-R18: fused SpMM+GEMM (16 nodes/block, 512 thr, full MFMA tile), saddr
//   gathers, batch-8, csr-fused Ta pre-scale, half-wave spmm64. sg = 67.6us,
//   internal gather rate 6.25 TB/s vs 7.3 standalone.
// R19: A/B on the VMEM-instruction-rate hypothesis: half-wave dwordx2
//   gathers in sg phase 1 -- lanes 0-31 own node A, 32-63 node B, 8B/lane:
//   ONE instruction reads TWO 256B rows. Same rows in flight (16/wave),
//   half the VMEM instructions + addressing VALU. Everything else unchanged.
// Pipeline: initprep -> bin -> scan -> fusedA2[gemm1|scatter] -> csr(+scaleT)
//   -> spmm_gemm<128> -> spmm_gemm<64> -> spmm64 = 8 launches.
// Requires n <= 65536 (16-bit packing; harness n = 50000).

constexpr int DIN = 256;
constexpr int HID = 128;
constexpr int DOUT = 64;
constexpr int MAXB = 1024;   // max buckets (n <= 65536)
constexpr int BSH = 6;       // 64 nodes per bucket
constexpr int EPB = 8192;    // edges per bin/scatter block

typedef unsigned short ushort_t;
typedef unsigned int uint_t;
typedef __attribute__((ext_vector_type(8))) short bf16x8;
typedef __attribute__((ext_vector_type(4))) float f32x4;

__device__ inline ushort_t f2bf(float f) {
  uint_t u = __float_as_uint(f);
  u += 0x7FFF + ((u >> 16) & 1);  // RNE
  return (ushort_t)(u >> 16);
}
__device__ inline float bf2f(ushort_t b) {
  return __uint_as_float(((uint_t)b) << 16);
}

// 32-bit-offset gather loads: uniform base + (c<<SH | lane_bytes) voffset.
// SH = log2(row bytes). Lets the compiler emit global_load saddr form.
template <int SH>
__device__ inline uint_t ldrow32(const ushort_t* __restrict__ t, int c, uint_t lb) {
  return *(const uint_t*)((const char*)t + ((((uint_t)c) << SH) | lb));
}
template <int SH>
__device__ inline uint2 ldrow64(const ushort_t* __restrict__ t, int c, uint_t lb) {
  return *(const uint2*)((const char*)t + ((((uint_t)c) << SH) | lb));
}

// ---------- weight prep (device fn): W[K][F] fp32 -> fragment bf16 hi/lo ----------
// Layout: Bp[t = n/16][s = k/32][lane = (k/8 % 4)*16 + n%16][j = k%8]

__device__ inline void wprep_one(const float* __restrict__ W, ushort_t* __restrict__ Bhi,
                                 ushort_t* __restrict__ Blo, int K, int F, int i) {
  int k = i / F, nn = i % F;
  int t = nn >> 4, s = k >> 5, q = (k >> 3) & 3, j = k & 7;
  int lane = q * 16 + (nn & 15);
  int KS = K >> 5;
  size_t idx = (((size_t)t * KS + s) * 64 + (size_t)lane) * 8 + j;
  float w = W[i];
  ushort_t h = f2bf(w);
  float r = w - bf2f(h);
  Bhi[idx] = h;
  Blo[idx] = f2bf(r);
}

// ---------- init: zero bucket_total + wprep x3 ----------

__global__ __launch_bounds__(256) void initprep_kernel(
    int* __restrict__ bucket_total, int iblocks,
    const float* __restrict__ W1, ushort_t* __restrict__ W1hi, ushort_t* __restrict__ W1lo,
    const float* __restrict__ W2, ushort_t* __restrict__ W2hi, ushort_t* __restrict__ W2lo,
    const float* __restrict__ W3, ushort_t* __restrict__ W3hi, ushort_t* __restrict__ W3lo) {
  if ((int)blockIdx.x < iblocks) {
    int i = blockIdx.x * 256 + threadIdx.x;
    if (i < MAXB) bucket_total[i] = 0;
  } else {
    int idx = ((int)blockIdx.x - iblocks) * 256 + threadIdx.x;
    constexpr int S1 = DIN * HID;        // 32768
    constexpr int S2 = S1 + HID * HID;   // 49152
    constexpr int S3 = S2 + HID * DOUT;  // 57344
    if (idx < S1) wprep_one(W1, W1hi, W1lo, DIN, HID, idx);
    else if (idx < S2) wprep_one(W2, W2hi, W2lo, HID, HID, idx - S1);
    else if (idx < S3) wprep_one(W3, W3hi, W3lo, HID, DOUT, idx - S2);
  }
}

// ---------- bin pass: per-block LDS histogram over buckets ----------
// One returning global atomic per (block,bucket) -> block's base within bucket.

__global__ __launch_bounds__(256) void bin_kernel(const int* __restrict__ dst, int e,
    int nbuckets, int* __restrict__ bucket_total, int* __restrict__ block_base) {
  __shared__ int h[MAXB];
  int tid = threadIdx.x;
  for (int i = tid; i < nbuckets; i += 256) h[i] = 0;
  __syncthreads();
  int base = blockIdx.x * EPB;
  int end = min(base + EPB, e);
  for (int i = base + tid; i < end; i += 256) atomicAdd(&h[dst[i] >> BSH], 1);
  __syncthreads();
  for (int i = tid; i < nbuckets; i += 256) {
    int v = h[i];
    if (v) block_base[(size_t)blockIdx.x * nbuckets + i] = atomicAdd(&bucket_total[i], v);
  }
}

// ---------- bucket scan: exclusive scan of bucket_total (+ sentinel) ----------

__global__ __launch_bounds__(256) void scan_buckets_kernel(const int* __restrict__ total,
    int* __restrict__ base, int nb) {
  __shared__ int sums[256];
  int t = threadIdx.x;
  int a[4];
  int ls = 0;
#pragma unroll
  for (int k = 0; k < 4; ++k) {
    int idx = t * 4 + k;
    a[k] = (idx < nb) ? total[idx] : 0;
    ls += a[k];
  }
  sums[t] = ls;
  __syncthreads();
  for (int off = 1; off < 256; off <<= 1) {
    int u = (t >= off) ? sums[t - off] : 0;
    __syncthreads();
    sums[t] += u;
    __syncthreads();
  }
  int run = sums[t] - ls;  // exclusive
#pragma unroll
  for (int k = 0; k < 4; ++k) {
    int idx = t * 4 + k;
    if (idx < nb) base[idx] = run;
    run += a[k];
  }
  if (t == 255) base[nb] = sums[255];  // sentinel = e
}

// ---------- split-bf16 MFMA GEMM (device fn) ----------
// 256 threads = 4 waves; 64 rows per block-id; wave w: rows +16w..+16w+15.
// acc = Ahi*Bhi + Alo*Bhi + Ahi*Blo (fp32 accum; lo*lo dropped, ~2^-18 rel).

template <int K, int F, bool SCALE>
__device__ inline void gemm_mfma_dev(const float* __restrict__ X,
    const ushort_t* __restrict__ Bhi, const ushort_t* __restrict__ Blo,
    const float* __restrict__ dinv, ushort_t* __restrict__ T, int n, int bid) {
  constexpr int NT = F / 16;   // n-tiles
  constexpr int KS = K / 32;   // k-steps
  int wave = threadIdx.x >> 6;
  int lane = threadIdx.x & 63;
  int q = lane >> 4;
  int m = lane & 15;
  int arow = bid * 64 + wave * 16 + m;
  bool valid = arow < n;
  const float* xrow = X + (size_t)arow * K;

  f32x4 acc[NT];
#pragma unroll
  for (int t = 0; t < NT; ++t) acc[t] = (f32x4){0.f, 0.f, 0.f, 0.f};

  for (int s = 0; s < KS; ++s) {
    float av[8];
    if (valid) {
      float4 u0 = *(const float4*)(xrow + s * 32 + q * 8);
      float4 u1 = *(const float4*)(xrow + s * 32 + q * 8 + 4);
      av[0] = u0.x; av[1] = u0.y; av[2] = u0.z; av[3] = u0.w;
      av[4] = u1.x; av[5] = u1.y; av[6] = u1.z; av[7] = u1.w;
    } else {
#pragma unroll
      for (int j = 0; j < 8; ++j) av[j] = 0.f;
    }
    bf16x8 ahi, alo;
#pragma unroll
    for (int j = 0; j < 8; ++j) {
      ushort_t h = f2bf(av[j]);
      ahi[j] = (short)h;
      alo[j] = (short)f2bf(av[j] - bf2f(h));
    }
#pragma unroll
    for (int t = 0; t < NT; ++t) {
      size_t boff = (((size_t)t * KS + s) * 64 + (size_t)lane) * 8;
      bf16x8 bh = *(const bf16x8*)(Bhi + boff);
      bf16x8 bl = *(const bf16x8*)(Blo + boff);
      acc[t] = __builtin_amdgcn_mfma_f32_16x16x32_bf16(ahi, bh, acc[t], 0, 0, 0);
      acc[t] = __builtin_amdgcn_mfma_f32_16x16x32_bf16(alo, bh, acc[t], 0, 0, 0);
      acc[t] = __builtin_amdgcn_mfma_f32_16x16x32_bf16(ahi, bl, acc[t], 0, 0, 0);
    }
  }

  int orow_base = bid * 64 + wave * 16 + q * 4;
#pragma unroll
  for (int r = 0; r < 4; ++r) {
    int orow = orow_base + r;
    if (orow >= n) continue;
    float sc = SCALE ? dinv[orow] : 1.0f;
    ushort_t* trow = T + (size_t)orow * F + m;
#pragma unroll
    for (int t = 0; t < NT; ++t) trow[t * 16] = f2bf(sc * acc[t][r]);
  }
}

// ---------- fused A2: [gemm1 unscaled | scatter into buckets] ----------
// scatter: LDS re-histogram gives rank within (block,bucket); position =
// bucket_base[b] + block_base[blk][b] + rank. Zero global atomics.

__global__ __launch_bounds__(256) void fusedA2_kernel(
    const float* __restrict__ X, const ushort_t* __restrict__ Bhi,
    const ushort_t* __restrict__ Blo, ushort_t* __restrict__ T, int n, int gblocks,
    const int* __restrict__ src, const int* __restrict__ dst,
    const int* __restrict__ bucket_base, const int* __restrict__ block_base,
    uint_t* __restrict__ binned, int e, int nbuckets) {
  if ((int)blockIdx.x < gblocks) {
    gemm_mfma_dev<DIN, HID, false>(X, Bhi, Blo, nullptr, T, n, blockIdx.x);
  } else {
    __shared__ int rkh[MAXB];
    __shared__ int cbase[MAXB];
    int tid = threadIdx.x;
    int blk = (int)blockIdx.x - gblocks;
    for (int i = tid; i < nbuckets; i += 256) {
      rkh[i] = 0;
      cbase[i] = bucket_base[i] + block_base[(size_t)blk * nbuckets + i];
    }
    __syncthreads();
    int base = blk * EPB;
    int end = min(base + EPB, e);
    for (int i = base + tid; i < end; i += 256) {
      int d = dst[i];
      int s = src[i];
      int b = d >> BSH;
      int r = atomicAdd(&rkh[b], 1);
      binned[cbase[b] + r] = ((uint_t)d << 16) | (uint_t)s;
    }
  }
}

// ---------- per-bucket CSR build + Ta pre-scale ----------
// Bucket = contiguous node range -> offsets are bucket-local; no global scan.
// Also scales this bucket's 64 Ta rows by dinv[row] in place (bf16) so the
// downstream sg1 gather needs NO per-edge dinv loads.

__global__ __launch_bounds__(256) void csr_kernel(const uint_t* __restrict__ binned,
    const int* __restrict__ bucket_base, int n, int* __restrict__ row_start,
    int* __restrict__ deg, float* __restrict__ dinv, int* __restrict__ col,
    ushort_t* __restrict__ Ta) {
  __shared__ int cnt[64];
  __shared__ int rk[64];
  __shared__ int rs[64];
  __shared__ float sdinv[64];
  __shared__ int ebs[2];
  int tid = threadIdx.x;
  int b = blockIdx.x;
  int node0 = b << BSH;
  if (tid < 64) { cnt[tid] = 0; rk[tid] = 0; }
  if (tid == 0) { ebs[0] = bucket_base[b]; ebs[1] = bucket_base[b + 1]; }
  __syncthreads();
  int ebase = ebs[0];
  int esz = ebs[1] - ebase;
  for (int i = tid; i < esz; i += 256)
    atomicAdd(&cnt[(int)(binned[ebase + i] >> 16) - node0], 1);
  __syncthreads();
  if (tid < 64) {
    int v = cnt[tid];
    int inc = v;
#pragma unroll
    for (int off = 1; off < 64; off <<= 1) {
      int u = __shfl_up(inc, off, 64);
      if (tid >= off) inc += u;
    }
    rs[tid] = inc - v;  // exclusive within bucket
    float di = rsqrtf((float)(v + 1));
    sdinv[tid] = di;
    int node = node0 + tid;
    if (node < n) {
      deg[node] = v + 1;                      // + self-loop
      dinv[node] = di;
      row_start[node] = ebase + (inc - v);
    }
  }
  __syncthreads();
  for (int i = tid; i < esz; i += 256) {
    uint_t p = binned[ebase + i];
    int l = (int)(p >> 16) - node0;
    int r = atomicAdd(&rk[l], 1);
    col[ebase + rs[l] + r] = (int)(p & 0xFFFFu);
  }
  // ---- scale Ta rows (bf16 in place): 64 rows x 16 uint4 each ----
  int nrows = min(64, n - node0);
  if (nrows > 0) {
    uint4* tw = (uint4*)Ta + ((size_t)node0 << 4);  // 16 uint4 per row
    int nv4 = nrows << 4;
    for (int i = tid; i < nv4; i += 256) {
      float sc = sdinv[i >> 4];
      uint4 w = tw[i];
      uint_t ww[4] = {w.x, w.y, w.z, w.w};
#pragma unroll
      for (int j = 0; j < 4; ++j) {
        float lo = sc * bf2f((ushort_t)(ww[j] & 0xFFFF));
        float hi = sc * bf2f((ushort_t)(ww[j] >> 16));
        ww[j] = (uint_t)f2bf(lo) | ((uint_t)f2bf(hi) << 16);
      }
      w.x = ww[0]; w.y = ww[1]; w.z = ww[2]; w.w = ww[3];
      tw[i] = w;
    }
  }
}

// ---------- fused SpMM + GEMM (inner layers), 16 nodes/block, 8 waves ----------
// Phase 1: half-wave node ownership -- lanes 0-31 own node A, 32-63 node B;
//          dwordx2 gathers (8B/lane, features 4hl..4hl+3): ONE VMEM inst reads
//          TWO 256B rows. Batch-8 predicated loop = 16 rows in flight/wave.
//          Rows pre-scaled by dinv -> pure adds.
// Phase 2: FULL 16-row x 128 @ 128xFOUT MFMA. FOUT=128: 8 waves x 1 tile;
//          FOUT=64: waves 0-3 compute, 4-7 retire after barrier.

template <int FOUT>
__global__ __launch_bounds__(512) void spmm_gemm_kernel(
    const ushort_t* __restrict__ t, const int* __restrict__ row_start,
    const int* __restrict__ deg, const int* __restrict__ col,
    const float* __restrict__ dinv, const float* __restrict__ bias,
    const ushort_t* __restrict__ Bhi, const ushort_t* __restrict__ Blo,
    ushort_t* __restrict__ Tout, int n) {
  constexpr int FIN = 128;      // row = 256 B -> shift 8
  constexpr int NPB = 16;       // nodes per block
  constexpr int LDW = FIN + 4;  // LDS row stride (floats; 528B = 33*16 aligned)
  __shared__ float agg[NPB][LDW];
  int wave = threadIdx.x >> 6;  // 0..7
  int lane = threadIdx.x & 63;
  int nb0 = (int)blockIdx.x * NPB;

  // ---- phase 1: gather-aggregate (half-wave node ownership) ----
  {
    int half = lane >> 5;
    int hl = lane & 31;
    int ln = wave * 2 + half;       // LDS row this half fills
    int node = nb0 + ln;
    bool hv = node < n;
    int vnode = hv ? node : 0;
    int rs = row_start[vnode];
    int e  = hv ? (deg[vnode] - 1) : 0;
    float di = hv ? dinv[vnode] : 0.f;
    uint_t lb = (uint_t)hl << 3;    // 8B granule: features 4hl..4hl+3

    float a0 = 0.f, a1 = 0.f, a2 = 0.f, a3 = 0.f;
    {
      uint2 s = ldrow64<8>(t, vnode, lb);
      a0 = bf2f((ushort_t)(s.x & 0xFFFF)); a1 = bf2f((ushort_t)(s.x >> 16));
      a2 = bf2f((ushort_t)(s.y & 0xFFFF)); a3 = bf2f((ushort_t)(s.y >> 16));
      if (!hv) { a0 = a1 = a2 = a3 = 0.f; }
    }
    int emax = max(e, __shfl_xor(e, 32));
    for (int k = 0; k < emax; k += 8) {
      int c[8];
      uint2 v[8];
#pragma unroll
      for (int j = 0; j < 8; ++j) c[j] = col[(k + j) < e ? (rs + k + j) : rs];
#pragma unroll
      for (int j = 0; j < 8; ++j) v[j] = ldrow64<8>(t, c[j], lb);
#pragma unroll
      for (int j = 0; j < 8; ++j) {
        if ((k + j) < e) {
          a0 += bf2f((ushort_t)(v[j].x & 0xFFFF));
          a1 += bf2f((ushort_t)(v[j].x >> 16));
          a2 += bf2f((ushort_t)(v[j].y & 0xFFFF));
          a3 += bf2f((ushort_t)(v[j].y >> 16));
        }
      }
    }
    float4 bb = *(const float4*)(bias + 4 * hl);
    float4 o;
    o.x = hv ? fmaxf(fmaf(di, a0, bb.x), 0.f) : 0.f;
    o.y = hv ? fmaxf(fmaf(di, a1, bb.y), 0.f) : 0.f;
    o.z = hv ? fmaxf(fmaf(di, a2, bb.z), 0.f) : 0.f;
    o.w = hv ? fmaxf(fmaf(di, a3, bb.w), 0.f) : 0.f;
    *(float4*)&agg[ln][4 * hl] = o;
  }
  __syncthreads();

  // ---- phase 2: FULL 16-row x 128 @ 128 x FOUT MFMA ----
  constexpr int NT = FOUT / 16;  // 8 (FOUT=128) or 4 (FOUT=64)
  constexpr int KS = FIN / 32;
  if (wave < NT) {
    int q = lane >> 4, m = lane & 15;
    f32x4 acc = (f32x4){0.f, 0.f, 0.f, 0.f};
    const float* arow = &agg[m][0];
#pragma unroll
    for (int s = 0; s < KS; ++s) {
      float4 u0 = *(const float4*)(arow + s * 32 + q * 8);
      float4 u1 = *(const float4*)(arow + s * 32 + q * 8 + 4);
      float av[8];
      av[0] = u0.x; av[1] = u0.y; av[2] = u0.z; av[3] = u0.w;
      av[4] = u1.x; av[5] = u1.y; av[6] = u1.z; av[7] = u1.w;
      bf16x8 ahi, alo;
#pragma unroll
      for (int j = 0; j < 8; ++j) {
        ushort_t h = f2bf(av[j]);
        ahi[j] = (short)h;
        alo[j] = (short)f2bf(av[j] - bf2f(h));
      }
      size_t boff = (((size_t)wave * KS + s) * 64 + (size_t)lane) * 8;
      bf16x8 bh = *(const bf16x8*)(Bhi + boff);
      bf16x8 bl = *(const bf16x8*)(Blo + boff);
      acc = __builtin_amdgcn_mfma_f32_16x16x32_bf16(ahi, bh, acc, 0, 0, 0);
      acc = __builtin_amdgcn_mfma_f32_16x16x32_bf16(alo, bh, acc, 0, 0, 0);
      acc = __builtin_amdgcn_mfma_f32_16x16x32_bf16(ahi, bl, acc, 0, 0, 0);
    }
#pragma unroll
    for (int r = 0; r < 4; ++r) {
      int orow = nb0 + q * 4 + r;
      if (orow >= n) continue;
      float sc = dinv[orow];
      Tout[(size_t)orow * FOUT + wave * 16 + m] = f2bf(sc * acc[r]);
    }
  }
}

// ---------- final CSR SpMM, half-wave layout ----------
// F=64 rows (128 B). Lanes 0-31 own node n0, lanes 32-63 own n1: each gather
// is a uint (4 B/lane, full row per half-wave). Per-half own-e loop, batch-8.

__global__ __launch_bounds__(256) void spmm64_kernel(const ushort_t* __restrict__ t,
    const int* __restrict__ row_start, const int* __restrict__ deg,
    const int* __restrict__ col, const float* __restrict__ dinv,
    const float* __restrict__ bias, float* __restrict__ out, int n) {
  int gw = (int)((blockIdx.x * 256u + threadIdx.x) >> 6);
  int lane = threadIdx.x & 63;
  int half = lane >> 5;
  int hl = lane & 31;
  int n0 = gw * 2;
  if (n0 >= n) return;
  int node = n0 + half;
  bool valid = node < n;
  int vnode = valid ? node : n0;
  int rs = row_start[vnode];
  int e  = valid ? (deg[vnode] - 1) : 0;
  float di = dinv[vnode];
  uint_t lb = (uint_t)hl << 2;

  uint_t su = ldrow32<7>(t, vnode, lb);
  float ax = bf2f((ushort_t)(su & 0xFFFF));
  float ay = bf2f((ushort_t)(su >> 16));

  for (int k = 0; k < e; k += 8) {
    int c[8];
    uint_t v[8];
#pragma unroll
    for (int j = 0; j < 8; ++j) c[j] = col[(k + j) < e ? (rs + k + j) : rs];
#pragma unroll
    for (int j = 0; j < 8; ++j) v[j] = ldrow32<7>(t, c[j], lb);
#pragma unroll
    for (int j = 0; j < 8; ++j) {
      if ((k + j) < e) {
        ax += bf2f((ushort_t)(v[j] & 0xFFFF));
        ay += bf2f((ushort_t)(v[j] >> 16));
      }
    }
  }
  if (valid) {
    float bx = bias[2 * hl], by = bias[2 * hl + 1];
    ax = fmaf(di, ax, bx);
    ay = fmaf(di, ay, by);
    float2 o;
    o.x = ax;
    o.y = ay;
    *(float2*)(out + (size_t)node * DOUT + 2 * hl) = o;
  }
}

// ---------- launch ----------

extern "C" void kernel_launch(void* const* d_in, const int* in_sizes, int n_in,
                              void* d_out, int out_size, void* d_ws, size_t ws_size,
                              hipStream_t stream) {
  const float* x  = (const float*)d_in[0];
  const float* W1 = (const float*)d_in[1];
  const float* b1 = (const float*)d_in[2];
  const float* W2 = (const float*)d_in[3];
  const float* b2 = (const float*)d_in[4];
  const float* W3 = (const float*)d_in[5];
  const float* b3 = (const float*)d_in[6];
  const int* ei   = (const int*)d_in[7];  // harness delivers integers as int32

  int n = in_sizes[0] / DIN;
  int e = in_sizes[7] / 2;
  const int* src = ei;
  const int* dst = ei + e;

  char* ws = (char*)d_ws;
  size_t off = 0;
  auto alloc = [&](size_t bytes) -> void* {
    off = (off + 255) & ~(size_t)255;
    void* p = ws + off;
    off += bytes;
    return p;
  };
  int nbuckets = (n + 63) >> BSH;          // <= MAXB for n <= 65536
  int nbin = (e + EPB - 1) / EPB;

  int*      bucket_total = (int*)alloc((size_t)MAXB * 4);
  int*      bucket_base  = (int*)alloc((size_t)(MAXB + 1) * 4);
  int*      block_base   = (int*)alloc((size_t)nbin * nbuckets * 4);
  uint_t*   binned       = (uint_t*)alloc((size_t)e * 4);
  int*      deg          = (int*)alloc((size_t)n * 4);
  float*    dinv         = (float*)alloc((size_t)n * 4);
  int*      row_start    = (int*)alloc((size_t)n * 4);
  int*      col          = (int*)alloc((size_t)e * 4);
  ushort_t* Ta           = (ushort_t*)alloc((size_t)n * HID * 2);  // bf16 rows
  ushort_t* Tb           = (ushort_t*)alloc((size_t)n * HID * 2);  // bf16 rows
  ushort_t* W1hi         = (ushort_t*)alloc((size_t)DIN * HID * 2);
  ushort_t* W1lo         = (ushort_t*)alloc((size_t)DIN * HID * 2);
  ushort_t* W2hi         = (ushort_t*)alloc((size_t)HID * HID * 2);
  ushort_t* W2lo         = (ushort_t*)alloc((size_t)HID * HID * 2);
  ushort_t* W3hi         = (ushort_t*)alloc((size_t)HID * DOUT * 2);
  ushort_t* W3lo         = (ushort_t*)alloc((size_t)HID * DOUT * 2);
  (void)ws_size;

  int gemm_blocks = (n + 63) / 64;
  int sg_blocks = (n + 15) / 16;            // fused spmm_gemm: 16 nodes/block
  int nwaves = (n + 1) / 2;                 // 2 nodes per wave (final spmm)
  int spmm_blocks = (nwaves + 3) / 4;       // 4 waves per block
  constexpr int WPREP_TOTAL = DIN * HID + HID * HID + HID * DOUT;  // 57344
  int wblocks = (WPREP_TOTAL + 255) / 256;  // 224
  int iblocks = MAXB / 256;                 // 4

  initprep_kernel<<<iblocks + wblocks, 256, 0, stream>>>(
      bucket_total, iblocks,
      W1, W1hi, W1lo, W2, W2hi, W2lo, W3, W3hi, W3lo);
  bin_kernel<<<nbin, 256, 0, stream>>>(dst, e, nbuckets, bucket_total, block_base);
  scan_buckets_kernel<<<1, 256, 0, stream>>>(bucket_total, bucket_base, nbuckets);
  fusedA2_kernel<<<gemm_blocks + nbin, 256, 0, stream>>>(
      x, W1hi, W1lo, Ta, n, gemm_blocks,
      src, dst, bucket_base, block_base, binned, e, nbuckets);
  csr_kernel<<<nbuckets, 256, 0, stream>>>(binned, bucket_base, n, row_start,
                                           deg, dinv, col, Ta);

  // layer 1 agg + layer 2 GEMM (fused): Ta (pre-scaled bf16) -> Tb (scaled bf16)
  spmm_gemm_kernel<HID><<<sg_blocks, 512, 0, stream>>>(
      Ta, row_start, deg, col, dinv, b1, W2hi, W2lo, Tb, n);
  // layer 2 agg + layer 3 GEMM (fused): Tb -> Ta (n x 64, scaled bf16)
  spmm_gemm_kernel<DOUT><<<sg_blocks, 512, 0, stream>>>(
      Tb, row_start, deg, col, dinv, b2, W3hi, W3lo, Ta, n);
  // layer 3 agg (final): Ta -> out (fp32) + b3
  spmm64_kernel<<<spmm_blocks, 256, 0, stream>>>(
      Ta, row_start, deg, col, dinv, b3, (float*)d_out, n);
}